// Round 20
// baseline (517.603 us; speedup 1.0000x reference)
//
#include <hip/hip_runtime.h>
#include <hip/hip_bf16.h>
#include <stdint.h>

typedef __bf16 bf16;
typedef __bf16 bf16x4 __attribute__((ext_vector_type(4)));
typedef __bf16 bf16x8 __attribute__((ext_vector_type(8)));
typedef float f32x4 __attribute__((ext_vector_type(4)));
typedef unsigned short ushort8 __attribute__((ext_vector_type(8)));

// ---- async global->LDS, 16B per lane. LDS dest wave-uniform base; HW adds lane*16.
__device__ __forceinline__ void gload16(const bf16* g, char* l) {
  __builtin_amdgcn_global_load_lds(
      reinterpret_cast<const __attribute__((address_space(1))) unsigned int*>(
          reinterpret_cast<uintptr_t>(g)),
      reinterpret_cast<__attribute__((address_space(3))) unsigned int*>(
          reinterpret_cast<uintptr_t>(l)),
      16, 0, 0);
}

#define VMCNT(n)  asm volatile("s_waitcnt vmcnt(" #n ")" ::: "memory")
#define LGKM0()   do { asm volatile("s_waitcnt lgkmcnt(0)" ::: "memory"); \
                       __builtin_amdgcn_sched_barrier(0); } while (0)
#define BAR()     __builtin_amdgcn_s_barrier()

// ---- f32 -> bf16 cast, 8 elems/thread, grid-stride ----
__global__ __launch_bounds__(256) void cast_bf16(const float* __restrict__ in,
                                                 bf16* __restrict__ out, int n8) {
  int i = blockIdx.x * blockDim.x + threadIdx.x;
  const int stride = gridDim.x * blockDim.x;
  for (; i < n8; i += stride) {
    const float4 v0 = reinterpret_cast<const float4*>(in)[i * 2];
    const float4 v1 = reinterpret_cast<const float4*>(in)[i * 2 + 1];
    bf16x8 o = { (bf16)v0.x, (bf16)v0.y, (bf16)v0.z, (bf16)v0.w,
                 (bf16)v1.x, (bf16)v1.y, (bf16)v1.z, (bf16)v1.w };
    reinterpret_cast<bf16x8*>(out)[i] = o;
  }
}

// ---- fallback rowsum of expS: one wave per row (4096 bf16), memory-bound ----
__global__ __launch_bounds__(256) void rowsum_bf16(const unsigned short* __restrict__ S,
                                                   float* __restrict__ sums) {
  const int row = blockIdx.x * 4 + (threadIdx.x >> 6);
  const int lane = threadIdx.x & 63;
  const unsigned short* r = S + (size_t)row * 4096;
  float s = 0.f;
#pragma unroll
  for (int i = 0; i < 8; ++i) {
    ushort8 v = *reinterpret_cast<const ushort8*>(r + i * 512 + lane * 8);
#pragma unroll
    for (int j = 0; j < 8; ++j) s += __uint_as_float(((unsigned)v[j]) << 16);
  }
#pragma unroll
  for (int o = 32; o; o >>= 1) s += __shfl_xor(s, o);
  if (lane == 0) sums[row] = s;
}

// ====== 8-phase NT GEMM, minimal-barrier wave-slip + 1-phase A-frag reg-prefetch ======
// C[M,N] = op(A[M,K].B[N,K]^T).  BM=256, BK=64, 512 thr = 8 waves.
// BN==256 (R19 barrier skeleton: 2 BAR / K-step):
//   q1 {read bb+a01(aA); PREFETCH a23(aB); stage A-lo(u+1); MFMA(aA)}
//   q2 {PREFETCH a45(aA); stage A-hi(u+1); MFMA(aB)}
//   q3 {BAR; PREFETCH a67(aB); stage B-lo(u+2); MFMA(aA)}
//   q4 {stage B-hi(u+2); vmcnt(4); MFMA(aB); BAR}
// Each MFMA cluster consumes frags read one phase EARLIER; the compiler's
// per-value counted lgkmcnt leaves the newest 4 reads in flight under the MFMA
// (intra-wave read/compute overlap -- the piece slip alone couldn't give; R5/R8
// nulls were in the lockstep regime).  Race ledger identical to R19:
//  - BAR(q3): all waves drained bb (compiler wait before q1 MFMA precedes it in
//    program order) => stB(b,u+2) safe vs B(u) reads.
//  - BAR(q4-end): collectivizes a67 drain (before q4 MFMA) => next stA(bn,u+1)
//    safe; collectivizes vmcnt(4) (FIFO: 12 outstanding, oldest 8 = tile u+1).
// BN==128 (G3 only): byte-identical to R14.
// EPI: 0 = acc*scale+aux[col] (bf16) | 1 = exp(acc*scale) (bf16; no-max softmax,
// logits |max|~3.5 << 88; + optional row partials) | 2 = acc/rowsum (f32).
template <int EPI, int BN>
__global__ __launch_bounds__(512, 2) void gemm8(
    const bf16* __restrict__ A, const bf16* __restrict__ B,
    const float* __restrict__ aux, float* __restrict__ psum,
    void* __restrict__ Cout, int M, int N, int K, float scale, int nparts) {
  constexpr int BUFSZ = 32768 + BN * 128;        // A 32KB + B
  constexpr int BOFF = 32768;
  constexpr int TM = (BN == 256) ? 128 : 64;
  constexpr int MI = TM / 16;
  constexpr int NI = 4;
  extern __shared__ char lds[];
  const int tid = threadIdx.x;
  const int lane = tid & 63, w = tid >> 6;

  // bijective XCD chunking (m204), n-fast within chunk (L2 A-reuse)
  const int gridN = N / BN;
  const int nwg = gridDim.x;
  const int orig = blockIdx.x;
  int wgid;
  { const int q = nwg >> 3, r = nwg & 7, x = orig & 7, rest = orig >> 3;
    wgid = (x < r ? x * (q + 1) : r * (q + 1) + (x - r) * q) + rest; }
  const int m0 = (wgid / gridN) * 256;
  const int n0 = (wgid % gridN) * BN;

  // staging source: pre-swizzled chunk so linear LDS dest = swizzled layout
  const int srow = lane >> 3;                         // 0..7
  const int scol = ((lane & 7) ^ srow) * 8;           // chunk^row&7, elems
  const bf16* gA = A + (size_t)(m0 + w * 8 + srow) * K + scol;
  const bf16* gB = B + (size_t)(n0 + w * 8 + srow) * K + scol;

  auto stA = [&](char* dst, int u, int h) {
    gload16(gA + (size_t)(h * 128) * K + (size_t)u * 64, dst + h * 16384 + w * 1024);
    gload16(gA + (size_t)(h * 128 + 64) * K + (size_t)u * 64, dst + h * 16384 + 8192 + w * 1024);
  };
  auto stB = [&](char* dst, int u, int h) {
    gload16(gB + (size_t)(h * 128) * K + (size_t)u * 64, dst + BOFF + h * 16384 + w * 1024);
    gload16(gB + (size_t)(h * 128 + 64) * K + (size_t)u * 64, dst + BOFF + h * 16384 + 8192 + w * 1024);
  };

  // fragment read bases (swizzled)
  const int fr = lane & 15, hi = lane >> 4;
  int wm, wn;
  if constexpr (BN == 256) { wm = w >> 2; wn = w & 3; }
  else                     { wm = w >> 1; wn = w & 1; }
  const int abase = (wm * TM + fr) * 128 + ((hi ^ (fr & 7)) << 4);
  const int bbase = BOFF + (wn * 64 + fr) * 128 + ((hi ^ (fr & 7)) << 4);
#define RD_A(b, mi, ks) (*(const bf16x8*)((b) + ((abase + (mi) * 2048) ^ ((ks) << 6))))
#define RD_B(b, ni, ks) (*(const bf16x8*)((b) + ((bbase + (ni) * 2048) ^ ((ks) << 6))))

  f32x4 acc[MI][NI] = {};
  const int NT = K >> 6;

  // prologue: A(0), B(0), B(1); prove A(0)+B(0)
  stA(lds, 0, 0); stA(lds, 0, 1);
  stB(lds, 0, 0);
  if constexpr (BN == 256) stB(lds, 0, 1);
  stB(lds + BUFSZ, 1, 0);
  if constexpr (BN == 256) { stB(lds + BUFSZ, 1, 1); VMCNT(4); }
  else                     { VMCNT(2); }
  BAR();

  for (int u = 0; u < NT; ++u) {
    char* b  = lds + (size_t)(u & 1) * BUFSZ;
    char* bn = lds + (size_t)((u + 1) & 1) * BUFSZ;
    bf16x8 bb[2][NI], aA[2][2], aB[2][2];
    const bool sA = (u + 1) < NT, sB = (u + 2) < NT;

    if constexpr (BN == 256) {
      // ---- q1: bb + a01 -> aA; prefetch a23 -> aB; stage A-lo(u+1); MFMA(aA) ----
      aA[0][0] = RD_A(b, 0, 0); aA[0][1] = RD_A(b, 0, 1);
      aA[1][0] = RD_A(b, 1, 0); aA[1][1] = RD_A(b, 1, 1);
#pragma unroll
      for (int ni = 0; ni < NI; ++ni) { bb[0][ni] = RD_B(b, ni, 0); bb[1][ni] = RD_B(b, ni, 1); }
      aB[0][0] = RD_A(b, 2, 0); aB[0][1] = RD_A(b, 2, 1);
      aB[1][0] = RD_A(b, 3, 0); aB[1][1] = RD_A(b, 3, 1);
      if (sA) stA(bn, u + 1, 0);
      __builtin_amdgcn_s_setprio(1);
#pragma unroll
      for (int m2 = 0; m2 < 2; ++m2)
#pragma unroll
        for (int ni = 0; ni < NI; ++ni) {
          acc[m2][ni] = __builtin_amdgcn_mfma_f32_16x16x32_bf16(aA[m2][0], bb[0][ni], acc[m2][ni], 0, 0, 0);
          acc[m2][ni] = __builtin_amdgcn_mfma_f32_16x16x32_bf16(aA[m2][1], bb[1][ni], acc[m2][ni], 0, 0, 0);
        }
      __builtin_amdgcn_s_setprio(0);
      // ---- q2: prefetch a45 -> aA; stage A-hi(u+1); MFMA(aB = a23) ----
      aA[0][0] = RD_A(b, 4, 0); aA[0][1] = RD_A(b, 4, 1);
      aA[1][0] = RD_A(b, 5, 0); aA[1][1] = RD_A(b, 5, 1);
      if (sA) stA(bn, u + 1, 1);
      __builtin_amdgcn_s_setprio(1);
#pragma unroll
      for (int m2 = 0; m2 < 2; ++m2)
#pragma unroll
        for (int ni = 0; ni < NI; ++ni) {
          acc[2 + m2][ni] = __builtin_amdgcn_mfma_f32_16x16x32_bf16(aB[m2][0], bb[0][ni], acc[2 + m2][ni], 0, 0, 0);
          acc[2 + m2][ni] = __builtin_amdgcn_mfma_f32_16x16x32_bf16(aB[m2][1], bb[1][ni], acc[2 + m2][ni], 0, 0, 0);
        }
      __builtin_amdgcn_s_setprio(0);
      // ---- q3: BAR; prefetch a67 -> aB; stage B-lo(u+2); MFMA(aA = a45) ----
      BAR();
      aB[0][0] = RD_A(b, 6, 0); aB[0][1] = RD_A(b, 6, 1);
      aB[1][0] = RD_A(b, 7, 0); aB[1][1] = RD_A(b, 7, 1);
      if (sB) stB(b, u + 2, 0);
      __builtin_amdgcn_s_setprio(1);
#pragma unroll
      for (int m2 = 0; m2 < 2; ++m2)
#pragma unroll
        for (int ni = 0; ni < NI; ++ni) {
          acc[4 + m2][ni] = __builtin_amdgcn_mfma_f32_16x16x32_bf16(aA[m2][0], bb[0][ni], acc[4 + m2][ni], 0, 0, 0);
          acc[4 + m2][ni] = __builtin_amdgcn_mfma_f32_16x16x32_bf16(aA[m2][1], bb[1][ni], acc[4 + m2][ni], 0, 0, 0);
        }
      __builtin_amdgcn_s_setprio(0);
      // ---- q4: stage B-hi(u+2); vmcnt(4); MFMA(aB = a67); END BAR ----
      if (sB) stB(b, u + 2, 1);
      if (sB) VMCNT(4); else VMCNT(0);
      __builtin_amdgcn_s_setprio(1);
#pragma unroll
      for (int m2 = 0; m2 < 2; ++m2)
#pragma unroll
        for (int ni = 0; ni < NI; ++ni) {
          acc[6 + m2][ni] = __builtin_amdgcn_mfma_f32_16x16x32_bf16(aB[m2][0], bb[0][ni], acc[6 + m2][ni], 0, 0, 0);
          acc[6 + m2][ni] = __builtin_amdgcn_mfma_f32_16x16x32_bf16(aB[m2][1], bb[1][ni], acc[6 + m2][ni], 0, 0, 0);
        }
      __builtin_amdgcn_s_setprio(0);
      BAR();   // re-lockstep: collectivizes vmcnt(4) + a67 drain
    } else {
      // ---- BN==128 (G3): byte-identical to R14 (2 barriers/phase) ----
      aA[0][0] = RD_A(b, 0, 0); aA[0][1] = RD_A(b, 0, 1);
      aA[1][0] = RD_A(b, 1, 0); aA[1][1] = RD_A(b, 1, 1);
#pragma unroll
      for (int ni = 0; ni < NI; ++ni) { bb[0][ni] = RD_B(b, ni, 0); bb[1][ni] = RD_B(b, ni, 1); }
      if (sA) { stA(bn, u + 1, 0); stA(bn, u + 1, 1); }
      BAR(); LGKM0();
      __builtin_amdgcn_s_setprio(1);
#pragma unroll
      for (int m2 = 0; m2 < 2; ++m2)
#pragma unroll
        for (int ni = 0; ni < NI; ++ni) {
          acc[m2][ni] = __builtin_amdgcn_mfma_f32_16x16x32_bf16(aA[m2][0], bb[0][ni], acc[m2][ni], 0, 0, 0);
          acc[m2][ni] = __builtin_amdgcn_mfma_f32_16x16x32_bf16(aA[m2][1], bb[1][ni], acc[m2][ni], 0, 0, 0);
        }
      __builtin_amdgcn_s_setprio(0);
      BAR();
      aA[0][0] = RD_A(b, 2, 0); aA[0][1] = RD_A(b, 2, 1);
      aA[1][0] = RD_A(b, 3, 0); aA[1][1] = RD_A(b, 3, 1);
      if (sB) stB(b, u + 2, 0);
      BAR(); LGKM0();
      __builtin_amdgcn_s_setprio(1);
#pragma unroll
      for (int m2 = 0; m2 < 2; ++m2)
#pragma unroll
        for (int ni = 0; ni < NI; ++ni) {
          acc[2 + m2][ni] = __builtin_amdgcn_mfma_f32_16x16x32_bf16(aA[m2][0], bb[0][ni], acc[2 + m2][ni], 0, 0, 0);
          acc[2 + m2][ni] = __builtin_amdgcn_mfma_f32_16x16x32_bf16(aA[m2][1], bb[1][ni], acc[2 + m2][ni], 0, 0, 0);
        }
      __builtin_amdgcn_s_setprio(0);
      if (sB) VMCNT(2); else VMCNT(0);
      BAR();
    }
  }
#undef RD_A
#undef RD_B

  // ---- EPI==2: gather this block's 256 row sums (nparts partials each) ----
  float* lsum = (float*)lds;
  if constexpr (EPI == 2) {
    if (tid < 256) {
      const float* p = aux + (size_t)(m0 + tid) * nparts;
      float s = 0.f;
      for (int bp = 0; bp < nparts; ++bp) s += p[bp];
      lsum[tid] = s;
    }
    __syncthreads();
  }

  // epilogue: C/D layout col = lane&15, row = (lane>>4)*4 + j  [m89-verified]
  const int lro = hi * 4;
  if constexpr (EPI == 2) {
#pragma unroll
    for (int mi = 0; mi < MI; ++mi)
#pragma unroll
      for (int j = 0; j < 4; ++j) {
        const int lr = wm * TM + mi * 16 + lro + j;
        const float inv = 1.0f / lsum[lr];   // same-addr across fr -> LDS broadcast
        const size_t grow = (size_t)(m0 + lr) * N;
#pragma unroll
        for (int ni = 0; ni < NI; ++ni)
          ((float*)Cout)[grow + n0 + wn * 64 + ni * 16 + fr] = acc[mi][ni][j] * inv;
      }
  } else {
    float rs[MI][4];
    if constexpr (EPI == 1) {
#pragma unroll
      for (int mi = 0; mi < MI; ++mi)
#pragma unroll
        for (int j = 0; j < 4; ++j) rs[mi][j] = 0.f;
    }
#pragma unroll
    for (int ni = 0; ni < NI; ++ni) {
      const int gcol = n0 + wn * 64 + ni * 16 + fr;
      float bvs = 0.f;
      if constexpr (EPI == 0) bvs = aux[gcol];
#pragma unroll
      for (int mi = 0; mi < MI; ++mi) {
        const int grow = m0 + wm * TM + mi * 16 + lro;
#pragma unroll
        for (int j = 0; j < 4; ++j) {
          float c = acc[mi][ni][j] * scale + bvs;
          if constexpr (EPI == 1) { c = __expf(c); rs[mi][j] += c; }
          ((bf16*)Cout)[(size_t)(grow + j) * N + gcol] = (bf16)c;
        }
      }
    }
    if constexpr (EPI == 1) {
      if (psum != nullptr) {
        float* wsum = (float*)lds;   // [4 wn][256 rows] = 4 KB (post-loop, LDS dead)
        __syncthreads();             // ensure all waves exited K-loop before reuse
#pragma unroll
        for (int mi = 0; mi < MI; ++mi)
#pragma unroll
          for (int j = 0; j < 4; ++j) {
            float s = rs[mi][j];
            s += __shfl_xor(s, 1); s += __shfl_xor(s, 2);
            s += __shfl_xor(s, 4); s += __shfl_xor(s, 8);
            if (fr == 0) wsum[wn * 256 + wm * TM + mi * 16 + lro + j] = s;
          }
        __syncthreads();
        if (tid < 256) {
          const float s = wsum[tid] + wsum[256 + tid] + wsum[512 + tid] + wsum[768 + tid];
          psum[(size_t)(m0 + tid) * 16 + (n0 >> 8)] = s;
        }
      }
    }
  }
}

// ------- prep: dicb[k,e] = bf16(dic[k,e])  AND  w3t[e,k] = bf16(prior[k]*dic[k,e]) -------
__global__ __launch_bounds__(256) void prep_dic(const float* __restrict__ dic,
                                                const float* __restrict__ prior,
                                                bf16* __restrict__ dicb,
                                                bf16* __restrict__ w3t) {
  const int KD = 4096, E = 2048;
  __shared__ bf16 t[64][72];
  const int k0 = blockIdx.x * 64, e0 = blockIdx.y * 64;
  const int tid = threadIdx.x;
  const int er = (tid & 15) * 4;
  const int kr = tid >> 4;
#pragma unroll
  for (int p = 0; p < 4; ++p) {
    const int k = kr + p * 16;
    const float pr = prior[k0 + k];
    const float4 v = *reinterpret_cast<const float4*>(dic + (size_t)(k0 + k) * E + e0 + er);
    bf16x4 db = { (bf16)v.x, (bf16)v.y, (bf16)v.z, (bf16)v.w };
    *reinterpret_cast<bf16x4*>(dicb + (size_t)(k0 + k) * E + e0 + er) = db;
    t[er + 0][k] = (bf16)(v.x * pr);
    t[er + 1][k] = (bf16)(v.y * pr);
    t[er + 2][k] = (bf16)(v.z * pr);
    t[er + 3][k] = (bf16)(v.w * pr);
  }
  __syncthreads();
  const int e = tid >> 2, kc = (tid & 3) * 16;
  ushort8 a = *reinterpret_cast<ushort8*>(&t[e][kc]);
  ushort8 b = *reinterpret_cast<ushort8*>(&t[e][kc + 8]);
  unsigned short* dst = (unsigned short*)w3t + (size_t)(e0 + e) * KD + k0 + kc;
  *reinterpret_cast<ushort8*>(dst) = a;
  *reinterpret_cast<ushort8*>(dst + 8) = b;
}

extern "C" void kernel_launch(void* const* d_in, const int* in_sizes, int n_in,
                              void* d_out, int out_size, void* d_ws, size_t ws_size,
                              hipStream_t stream) {
  const float* y     = (const float*)d_in[0];  // [16384,1024]
  const float* Wy_w  = (const float*)d_in[1];  // [1024,1024]
  const float* Wy_b  = (const float*)d_in[2];  // [1024]
  const float* Wz_w  = (const float*)d_in[3];  // [1024,2048]
  const float* Wz_b  = (const float*)d_in[4];  // [1024]
  const float* dic   = (const float*)d_in[5];  // [4096,2048]
  const float* prior = (const float*)d_in[6];  // [4096]
  float* z = (float*)d_out;                    // [16384,2048]

  const int M = 16384, D = 1024, E = 2048, KD = 4096;

  char* ws = (char*)d_ws;
  bf16* w3t  = (bf16*)(ws);                        // [0, 16M)
  bf16* h    = (bf16*)(ws + ((size_t)16 << 20));   // [16M, 48M)
  bf16* dzb  = (bf16*)(ws + ((size_t)48 << 20));   // [48M, 56M)
  bf16* S    = (bf16*)(ws + ((size_t)56 << 20));   // [56M, 184M)  expS after G4
  bf16* yb   = (bf16*)(ws + ((size_t)56 << 20));   // cast overlays inside S (dead pre-G4)
  bf16* Wyb  = (bf16*)(ws + ((size_t)88 << 20));
  bf16* Wzb  = (bf16*)(ws + ((size_t)90 << 20));
  bf16* dicb = (bf16*)(ws + ((size_t)94 << 20));

  // psum TAIL slab [184M, 185M): outside every live region during G4.
  const bool fused_sum = ws_size >= ((size_t)185 << 20);
  float* psum = fused_sum ? (float*)(ws + ((size_t)184 << 20)) : nullptr;
  float* sums = (float*)(ws + ((size_t)16 << 20));  // fallback: h region, dead after G4

  // 0) pre-cast f32 operands to bf16 (dic cast fused into prep_dic)
  cast_bf16<<<2048, 256, 0, stream>>>(y, yb, M * D / 8);
  cast_bf16<<<512, 256, 0, stream>>>(Wy_w, Wyb, D * D / 8);
  cast_bf16<<<512, 256, 0, stream>>>(Wz_w, Wzb, D * E / 8);
  // 1) dicb + w3t from one read of dic
  prep_dic<<<dim3(KD / 64, E / 64), 256, 0, stream>>>(dic, prior, dicb, w3t);
  // 2) h = yb . Wyb^T + Wy_b   -> bf16 [16384,1024]   grid 256
  gemm8<0, 256><<<(M / 256) * (D / 256), 512, 131072, stream>>>(
      yb, Wyb, Wy_b, nullptr, h, M, D, D, 1.0f, 0);
  // 3) dz = dicb . Wzb^T + Wz_b -> bf16 [4096,1024]   grid 128
  gemm8<0, 128><<<(KD / 256) * (D / 128), 512, 98304, stream>>>(
      dicb, Wzb, Wz_b, nullptr, dzb, KD, D, E, 1.0f, 0);
  // 4) expS = exp(h . dz^T / 32) -> bf16 [16384,4096] grid 1024
  gemm8<1, 256><<<(M / 256) * (KD / 256), 512, 131072, stream>>>(
      h, dzb, nullptr, psum, S, M, KD, D, 0.03125f, 0);
  if (!fused_sum) {
    rowsum_bf16<<<M / 4, 256, 0, stream>>>((const unsigned short*)S, sums);
  }
  // 5+6) z = (expS . w3t^T) / rowsum -> f32 [16384,2048]  grid 512
  gemm8<2, 256><<<(M / 256) * (E / 256), 512, 131072, stream>>>(
      S, w3t, fused_sum ? psum : sums, nullptr, z, M, E, KD, 1.0f,
      fused_sum ? 16 : 1);
}

// Round 21
// 512.454 us; speedup vs baseline: 1.0100x; 1.0100x over previous
//
#include <hip/hip_runtime.h>
#include <hip/hip_bf16.h>
#include <stdint.h>

typedef __bf16 bf16;
typedef __bf16 bf16x4 __attribute__((ext_vector_type(4)));
typedef __bf16 bf16x8 __attribute__((ext_vector_type(8)));
typedef float f32x4 __attribute__((ext_vector_type(4)));
typedef unsigned short ushort8 __attribute__((ext_vector_type(8)));

// ---- async global->LDS, 16B per lane. LDS dest wave-uniform base; HW adds lane*16.
__device__ __forceinline__ void gload16(const bf16* g, char* l) {
  __builtin_amdgcn_global_load_lds(
      reinterpret_cast<const __attribute__((address_space(1))) unsigned int*>(
          reinterpret_cast<uintptr_t>(g)),
      reinterpret_cast<__attribute__((address_space(3))) unsigned int*>(
          reinterpret_cast<uintptr_t>(l)),
      16, 0, 0);
}

#define VMCNT(n)  asm volatile("s_waitcnt vmcnt(" #n ")" ::: "memory")
#define LGKM0()   do { asm volatile("s_waitcnt lgkmcnt(0)" ::: "memory"); \
                       __builtin_amdgcn_sched_barrier(0); } while (0)
#define BAR()     __builtin_amdgcn_s_barrier()

// ---- merged f32 -> bf16 cast over three regions (one launch) ----
__global__ __launch_bounds__(256) void cast3_bf16(
    const float* __restrict__ a, bf16* __restrict__ ao, int na,
    const float* __restrict__ b, bf16* __restrict__ bo, int nb,
    const float* __restrict__ c, bf16* __restrict__ co, int nc) {
  int i = blockIdx.x * blockDim.x + threadIdx.x;
  const int stride = gridDim.x * blockDim.x;
  const int tot = na + nb + nc;
  for (; i < tot; i += stride) {
    const float* src; bf16* dst; int j;
    if (i < na)            { src = a; dst = ao; j = i; }
    else if (i < na + nb)  { src = b; dst = bo; j = i - na; }
    else                   { src = c; dst = co; j = i - na - nb; }
    const float4 v0 = reinterpret_cast<const float4*>(src)[j * 2];
    const float4 v1 = reinterpret_cast<const float4*>(src)[j * 2 + 1];
    bf16x8 o = { (bf16)v0.x, (bf16)v0.y, (bf16)v0.z, (bf16)v0.w,
                 (bf16)v1.x, (bf16)v1.y, (bf16)v1.z, (bf16)v1.w };
    reinterpret_cast<bf16x8*>(dst)[j] = o;
  }
}

// ---- fallback rowsum of expS: one wave per row (4096 bf16), memory-bound ----
__global__ __launch_bounds__(256) void rowsum_bf16(const unsigned short* __restrict__ S,
                                                   float* __restrict__ sums) {
  const int row = blockIdx.x * 4 + (threadIdx.x >> 6);
  const int lane = threadIdx.x & 63;
  const unsigned short* r = S + (size_t)row * 4096;
  float s = 0.f;
#pragma unroll
  for (int i = 0; i < 8; ++i) {
    ushort8 v = *reinterpret_cast<const ushort8*>(r + i * 512 + lane * 8);
#pragma unroll
    for (int j = 0; j < 8; ++j) s += __uint_as_float(((unsigned)v[j]) << 16);
  }
#pragma unroll
  for (int o = 32; o; o >>= 1) s += __shfl_xor(s, o);
  if (lane == 0) sums[row] = s;
}

// ============ 8-phase NT GEMM, MINIMAL-BARRIER wave-slip (R19 body, verified) ============
// C[M,N] = op(A[M,K].B[N,K]^T).  BM=256, BK=64, 512 thr = 8 waves.
// BN==256 (R19-verified, G6 244us / MfmaUtil 49.7 / 0 conflicts):
//   q1 {reads B+A01; stage A-lo(u+1); lgkm0; MFMA}      (no barrier)
//   q2 {reads A23;   stage A-hi(u+1); lgkm0; MFMA}      (no barrier)
//   q3 {BAR; reads A45; stage B-lo(u+2); lgkm0; MFMA}
//   q4 {reads A67; stage B-hi(u+2); vmcnt(4); lgkm0; MFMA; BAR}
// Ledger: BAR(q3) collectivizes q1/q2 lgkm0 => all B(u)-reads drained before any
// stB(b,u+2).  BAR(q4-end) collectivizes lgkm0(q4) (next stA(bn,u+1) safe) and
// vmcnt(4) (FIFO: 12 outstanding, oldest 8 = tile u+1 => proven).
// BN==128 (G3), NEW this round -- same slip mechanism, 2 BAR/K-step:
//   q1 {reads bb+a01; stage A-lo+hi(u+1); lgkm0; MFMA}  (no barrier)
//   q2 {BAR; reads a23; stage B(u+2); lgkm0; vmcnt(2); MFMA; BAR}
// Ledger: BAR(q2-start) collectivizes lgkm0(q1) => bb drained before stB(b,u+2).
// BAR(q2-end) collectivizes lgkm0(q2) (a23 of bn drained before next q1's
// stA(bn,u+1)) and vmcnt(2) (FIFO: 4 outstanding, oldest 2 = A(u+1) => proven;
// B(u+1) proven one step earlier by the same wait).
// EPI: 0 = acc*scale+aux[col] (bf16) | 1 = exp(acc*scale) (bf16; no-max softmax,
// logits |max|~3.5 << 88; + optional row partials) | 2 = acc/rowsum (f32).
template <int EPI, int BN>
__global__ __launch_bounds__(512, 2) void gemm8(
    const bf16* __restrict__ A, const bf16* __restrict__ B,
    const float* __restrict__ aux, float* __restrict__ psum,
    void* __restrict__ Cout, int M, int N, int K, float scale, int nparts) {
  constexpr int BUFSZ = 32768 + BN * 128;        // A 32KB + B
  constexpr int BOFF = 32768;
  constexpr int TM = (BN == 256) ? 128 : 64;
  constexpr int MI = TM / 16;
  constexpr int NI = 4;
  extern __shared__ char lds[];
  const int tid = threadIdx.x;
  const int lane = tid & 63, w = tid >> 6;

  // bijective XCD chunking (m204), n-fast within chunk (L2 A-reuse)
  const int gridN = N / BN;
  const int nwg = gridDim.x;
  const int orig = blockIdx.x;
  int wgid;
  { const int q = nwg >> 3, r = nwg & 7, x = orig & 7, rest = orig >> 3;
    wgid = (x < r ? x * (q + 1) : r * (q + 1) + (x - r) * q) + rest; }
  const int m0 = (wgid / gridN) * 256;
  const int n0 = (wgid % gridN) * BN;

  // staging source: pre-swizzled chunk so linear LDS dest = swizzled layout
  const int srow = lane >> 3;                         // 0..7
  const int scol = ((lane & 7) ^ srow) * 8;           // chunk^row&7, elems
  const bf16* gA = A + (size_t)(m0 + w * 8 + srow) * K + scol;
  const bf16* gB = B + (size_t)(n0 + w * 8 + srow) * K + scol;

  auto stA = [&](char* dst, int u, int h) {
    gload16(gA + (size_t)(h * 128) * K + (size_t)u * 64, dst + h * 16384 + w * 1024);
    gload16(gA + (size_t)(h * 128 + 64) * K + (size_t)u * 64, dst + h * 16384 + 8192 + w * 1024);
  };
  auto stB = [&](char* dst, int u, int h) {
    gload16(gB + (size_t)(h * 128) * K + (size_t)u * 64, dst + BOFF + h * 16384 + w * 1024);
    gload16(gB + (size_t)(h * 128 + 64) * K + (size_t)u * 64, dst + BOFF + h * 16384 + 8192 + w * 1024);
  };

  // fragment read bases (swizzled)
  const int fr = lane & 15, hi = lane >> 4;
  int wm, wn;
  if constexpr (BN == 256) { wm = w >> 2; wn = w & 3; }
  else                     { wm = w >> 1; wn = w & 1; }
  const int abase = (wm * TM + fr) * 128 + ((hi ^ (fr & 7)) << 4);
  const int bbase = BOFF + (wn * 64 + fr) * 128 + ((hi ^ (fr & 7)) << 4);
#define RD_A(b, mi, ks) (*(const bf16x8*)((b) + ((abase + (mi) * 2048) ^ ((ks) << 6))))
#define RD_B(b, ni, ks) (*(const bf16x8*)((b) + ((bbase + (ni) * 2048) ^ ((ks) << 6))))

  f32x4 acc[MI][NI] = {};
  const int NT = K >> 6;

  // prologue: A(0), B(0), B(1); prove A(0)+B(0)
  stA(lds, 0, 0); stA(lds, 0, 1);
  stB(lds, 0, 0);
  if constexpr (BN == 256) stB(lds, 0, 1);
  stB(lds + BUFSZ, 1, 0);
  if constexpr (BN == 256) { stB(lds + BUFSZ, 1, 1); VMCNT(4); }
  else                     { VMCNT(2); }
  BAR();

  for (int u = 0; u < NT; ++u) {
    char* b  = lds + (size_t)(u & 1) * BUFSZ;
    char* bn = lds + (size_t)((u + 1) & 1) * BUFSZ;
    bf16x8 bb[2][NI], a[2][2];
    const bool sA = (u + 1) < NT, sB = (u + 2) < NT;

    if constexpr (BN == 256) {
      // ---- q1: B all + A(0,1); stage A-lo(u+1); lgkm0; MFMA  (no barrier) ----
      a[0][0] = RD_A(b, 0, 0); a[0][1] = RD_A(b, 0, 1);
      a[1][0] = RD_A(b, 1, 0); a[1][1] = RD_A(b, 1, 1);
#pragma unroll
      for (int ni = 0; ni < NI; ++ni) { bb[0][ni] = RD_B(b, ni, 0); bb[1][ni] = RD_B(b, ni, 1); }
      if (sA) stA(bn, u + 1, 0);
      LGKM0();
      __builtin_amdgcn_s_setprio(1);
#pragma unroll
      for (int m2 = 0; m2 < 2; ++m2)
#pragma unroll
        for (int ni = 0; ni < NI; ++ni) {
          acc[m2][ni] = __builtin_amdgcn_mfma_f32_16x16x32_bf16(a[m2][0], bb[0][ni], acc[m2][ni], 0, 0, 0);
          acc[m2][ni] = __builtin_amdgcn_mfma_f32_16x16x32_bf16(a[m2][1], bb[1][ni], acc[m2][ni], 0, 0, 0);
        }
      __builtin_amdgcn_s_setprio(0);
      // ---- q2: A(2,3); stage A-hi(u+1); lgkm0; MFMA  (no barrier) ----
      a[0][0] = RD_A(b, 2, 0); a[0][1] = RD_A(b, 2, 1);
      a[1][0] = RD_A(b, 3, 0); a[1][1] = RD_A(b, 3, 1);
      if (sA) stA(bn, u + 1, 1);
      LGKM0();
      __builtin_amdgcn_s_setprio(1);
#pragma unroll
      for (int m2 = 0; m2 < 2; ++m2)
#pragma unroll
        for (int ni = 0; ni < NI; ++ni) {
          acc[2 + m2][ni] = __builtin_amdgcn_mfma_f32_16x16x32_bf16(a[m2][0], bb[0][ni], acc[2 + m2][ni], 0, 0, 0);
          acc[2 + m2][ni] = __builtin_amdgcn_mfma_f32_16x16x32_bf16(a[m2][1], bb[1][ni], acc[2 + m2][ni], 0, 0, 0);
        }
      __builtin_amdgcn_s_setprio(0);
      // ---- q3: BAR (collectivizes q1/q2 drains); A(4,5); stage B-lo(u+2) ----
      BAR();
      a[0][0] = RD_A(b, 4, 0); a[0][1] = RD_A(b, 4, 1);
      a[1][0] = RD_A(b, 5, 0); a[1][1] = RD_A(b, 5, 1);
      if (sB) stB(b, u + 2, 0);
      LGKM0();
      __builtin_amdgcn_s_setprio(1);
#pragma unroll
      for (int m2 = 0; m2 < 2; ++m2)
#pragma unroll
        for (int ni = 0; ni < NI; ++ni) {
          acc[4 + m2][ni] = __builtin_amdgcn_mfma_f32_16x16x32_bf16(a[m2][0], bb[0][ni], acc[4 + m2][ni], 0, 0, 0);
          acc[4 + m2][ni] = __builtin_amdgcn_mfma_f32_16x16x32_bf16(a[m2][1], bb[1][ni], acc[4 + m2][ni], 0, 0, 0);
        }
      __builtin_amdgcn_s_setprio(0);
      // ---- q4: A(6,7); stage B-hi(u+2); vmcnt(4); lgkm0; MFMA; END BAR ----
      a[0][0] = RD_A(b, 6, 0); a[0][1] = RD_A(b, 6, 1);
      a[1][0] = RD_A(b, 7, 0); a[1][1] = RD_A(b, 7, 1);
      if (sB) stB(b, u + 2, 1);
      if (sB) VMCNT(4); else VMCNT(0);
      LGKM0();
      __builtin_amdgcn_s_setprio(1);
#pragma unroll
      for (int m2 = 0; m2 < 2; ++m2)
#pragma unroll
        for (int ni = 0; ni < NI; ++ni) {
          acc[6 + m2][ni] = __builtin_amdgcn_mfma_f32_16x16x32_bf16(a[m2][0], bb[0][ni], acc[6 + m2][ni], 0, 0, 0);
          acc[6 + m2][ni] = __builtin_amdgcn_mfma_f32_16x16x32_bf16(a[m2][1], bb[1][ni], acc[6 + m2][ni], 0, 0, 0);
        }
      __builtin_amdgcn_s_setprio(0);
      BAR();   // re-lockstep: collectivizes vmcnt(4) + lgkm0(q4)
    } else {
      // ---- BN==128 (G3) slip: q1 {reads; stage A(u+1); lgkm0; MFMA} no barrier ----
      a[0][0] = RD_A(b, 0, 0); a[0][1] = RD_A(b, 0, 1);
      a[1][0] = RD_A(b, 1, 0); a[1][1] = RD_A(b, 1, 1);
#pragma unroll
      for (int ni = 0; ni < NI; ++ni) { bb[0][ni] = RD_B(b, ni, 0); bb[1][ni] = RD_B(b, ni, 1); }
      if (sA) { stA(bn, u + 1, 0); stA(bn, u + 1, 1); }
      LGKM0();
      __builtin_amdgcn_s_setprio(1);
#pragma unroll
      for (int m2 = 0; m2 < 2; ++m2)
#pragma unroll
        for (int ni = 0; ni < NI; ++ni) {
          acc[m2][ni] = __builtin_amdgcn_mfma_f32_16x16x32_bf16(a[m2][0], bb[0][ni], acc[m2][ni], 0, 0, 0);
          acc[m2][ni] = __builtin_amdgcn_mfma_f32_16x16x32_bf16(a[m2][1], bb[1][ni], acc[m2][ni], 0, 0, 0);
        }
      __builtin_amdgcn_s_setprio(0);
      // ---- q2: BAR (collectivizes bb drain); a23; stage B(u+2); vmcnt(2); MFMA; BAR ----
      BAR();
      a[0][0] = RD_A(b, 2, 0); a[0][1] = RD_A(b, 2, 1);
      a[1][0] = RD_A(b, 3, 0); a[1][1] = RD_A(b, 3, 1);
      if (sB) stB(b, u + 2, 0);
      if (sB) VMCNT(2); else VMCNT(0);
      LGKM0();
      __builtin_amdgcn_s_setprio(1);
#pragma unroll
      for (int m2 = 0; m2 < 2; ++m2)
#pragma unroll
        for (int ni = 0; ni < NI; ++ni) {
          acc[2 + m2][ni] = __builtin_amdgcn_mfma_f32_16x16x32_bf16(a[m2][0], bb[0][ni], acc[2 + m2][ni], 0, 0, 0);
          acc[2 + m2][ni] = __builtin_amdgcn_mfma_f32_16x16x32_bf16(a[m2][1], bb[1][ni], acc[2 + m2][ni], 0, 0, 0);
        }
      __builtin_amdgcn_s_setprio(0);
      BAR();   // collectivizes vmcnt(2) + lgkm0(q2)
    }
  }
#undef RD_A
#undef RD_B

  // ---- EPI==2: gather this block's 256 row sums (nparts partials each) ----
  float* lsum = (float*)lds;
  if constexpr (EPI == 2) {
    if (tid < 256) {
      const float* p = aux + (size_t)(m0 + tid) * nparts;
      float s = 0.f;
      for (int bp = 0; bp < nparts; ++bp) s += p[bp];
      lsum[tid] = s;
    }
    __syncthreads();
  }

  // epilogue: C/D layout col = lane&15, row = (lane>>4)*4 + j  [m89-verified]
  const int lro = hi * 4;
  if constexpr (EPI == 2) {
#pragma unroll
    for (int mi = 0; mi < MI; ++mi)
#pragma unroll
      for (int j = 0; j < 4; ++j) {
        const int lr = wm * TM + mi * 16 + lro + j;
        const float inv = 1.0f / lsum[lr];   // same-addr across fr -> LDS broadcast
        const size_t grow = (size_t)(m0 + lr) * N;
#pragma unroll
        for (int ni = 0; ni < NI; ++ni)
          ((float*)Cout)[grow + n0 + wn * 64 + ni * 16 + fr] = acc[mi][ni][j] * inv;
      }
  } else {
    float rs[MI][4];
    if constexpr (EPI == 1) {
#pragma unroll
      for (int mi = 0; mi < MI; ++mi)
#pragma unroll
        for (int j = 0; j < 4; ++j) rs[mi][j] = 0.f;
    }
#pragma unroll
    for (int ni = 0; ni < NI; ++ni) {
      const int gcol = n0 + wn * 64 + ni * 16 + fr;
      float bvs = 0.f;
      if constexpr (EPI == 0) bvs = aux[gcol];
#pragma unroll
      for (int mi = 0; mi < MI; ++mi) {
        const int grow = m0 + wm * TM + mi * 16 + lro;
#pragma unroll
        for (int j = 0; j < 4; ++j) {
          float c = acc[mi][ni][j] * scale + bvs;
          if constexpr (EPI == 1) { c = __expf(c); rs[mi][j] += c; }
          ((bf16*)Cout)[(size_t)(grow + j) * N + gcol] = (bf16)c;
        }
      }
    }
    if constexpr (EPI == 1) {
      if (psum != nullptr) {
        float* wsum = (float*)lds;   // [4 wn][256 rows] = 4 KB (post-loop, LDS dead)
        __syncthreads();             // ensure all waves exited K-loop before reuse
#pragma unroll
        for (int mi = 0; mi < MI; ++mi)
#pragma unroll
          for (int j = 0; j < 4; ++j) {
            float s = rs[mi][j];
            s += __shfl_xor(s, 1); s += __shfl_xor(s, 2);
            s += __shfl_xor(s, 4); s += __shfl_xor(s, 8);
            if (fr == 0) wsum[wn * 256 + wm * TM + mi * 16 + lro + j] = s;
          }
        __syncthreads();
        if (tid < 256) {
          const float s = wsum[tid] + wsum[256 + tid] + wsum[512 + tid] + wsum[768 + tid];
          psum[(size_t)(m0 + tid) * 16 + (n0 >> 8)] = s;
        }
      }
    }
  }
}

// ------- prep: dicb[k,e] = bf16(dic[k,e])  AND  w3t[e,k] = bf16(prior[k]*dic[k,e]) -------
__global__ __launch_bounds__(256) void prep_dic(const float* __restrict__ dic,
                                                const float* __restrict__ prior,
                                                bf16* __restrict__ dicb,
                                                bf16* __restrict__ w3t) {
  const int KD = 4096, E = 2048;
  __shared__ bf16 t[64][72];
  const int k0 = blockIdx.x * 64, e0 = blockIdx.y * 64;
  const int tid = threadIdx.x;
  const int er = (tid & 15) * 4;
  const int kr = tid >> 4;
#pragma unroll
  for (int p = 0; p < 4; ++p) {
    const int k = kr + p * 16;
    const float pr = prior[k0 + k];
    const float4 v = *reinterpret_cast<const float4*>(dic + (size_t)(k0 + k) * E + e0 + er);
    bf16x4 db = { (bf16)v.x, (bf16)v.y, (bf16)v.z, (bf16)v.w };
    *reinterpret_cast<bf16x4*>(dicb + (size_t)(k0 + k) * E + e0 + er) = db;
    t[er + 0][k] = (bf16)(v.x * pr);
    t[er + 1][k] = (bf16)(v.y * pr);
    t[er + 2][k] = (bf16)(v.z * pr);
    t[er + 3][k] = (bf16)(v.w * pr);
  }
  __syncthreads();
  const int e = tid >> 2, kc = (tid & 3) * 16;
  ushort8 a = *reinterpret_cast<ushort8*>(&t[e][kc]);
  ushort8 b = *reinterpret_cast<ushort8*>(&t[e][kc + 8]);
  unsigned short* dst = (unsigned short*)w3t + (size_t)(e0 + e) * KD + k0 + kc;
  *reinterpret_cast<ushort8*>(dst) = a;
  *reinterpret_cast<ushort8*>(dst + 8) = b;
}

extern "C" void kernel_launch(void* const* d_in, const int* in_sizes, int n_in,
                              void* d_out, int out_size, void* d_ws, size_t ws_size,
                              hipStream_t stream) {
  const float* y     = (const float*)d_in[0];  // [16384,1024]
  const float* Wy_w  = (const float*)d_in[1];  // [1024,1024]
  const float* Wy_b  = (const float*)d_in[2];  // [1024]
  const float* Wz_w  = (const float*)d_in[3];  // [1024,2048]
  const float* Wz_b  = (const float*)d_in[4];  // [1024]
  const float* dic   = (const float*)d_in[5];  // [4096,2048]
  const float* prior = (const float*)d_in[6];  // [4096]
  float* z = (float*)d_out;                    // [16384,2048]

  const int M = 16384, D = 1024, E = 2048, KD = 4096;

  char* ws = (char*)d_ws;
  bf16* w3t  = (bf16*)(ws);                        // [0, 16M)
  bf16* h    = (bf16*)(ws + ((size_t)16 << 20));   // [16M, 48M)
  bf16* dzb  = (bf16*)(ws + ((size_t)48 << 20));   // [48M, 56M)
  bf16* S    = (bf16*)(ws + ((size_t)56 << 20));   // [56M, 184M)  expS after G4
  bf16* yb   = (bf16*)(ws + ((size_t)56 << 20));   // cast overlays inside S (dead pre-G4)
  bf16* Wyb  = (bf16*)(ws + ((size_t)88 << 20));
  bf16* Wzb  = (bf16*)(ws + ((size_t)90 << 20));
  bf16* dicb = (bf16*)(ws + ((size_t)94 << 20));

  // psum TAIL slab [184M, 185M): outside every live region during G4.
  const bool fused_sum = ws_size >= ((size_t)185 << 20);
  float* psum = fused_sum ? (float*)(ws + ((size_t)184 << 20)) : nullptr;
  float* sums = (float*)(ws + ((size_t)16 << 20));  // fallback: h region, dead after G4

  // 0) pre-cast f32 operands to bf16 in ONE launch (dic cast fused into prep_dic)
  cast3_bf16<<<2048, 256, 0, stream>>>(y, yb, M * D / 8,
                                       Wy_w, Wyb, D * D / 8,
                                       Wz_w, Wzb, D * E / 8);
  // 1) dicb + w3t from one read of dic
  prep_dic<<<dim3(KD / 64, E / 64), 256, 0, stream>>>(dic, prior, dicb, w3t);
  // 2) h = yb . Wyb^T + Wy_b   -> bf16 [16384,1024]   grid 256
  gemm8<0, 256><<<(M / 256) * (D / 256), 512, 131072, stream>>>(
      yb, Wyb, Wy_b, nullptr, h, M, D, D, 1.0f, 0);
  // 3) dz = dicb . Wzb^T + Wz_b -> bf16 [4096,1024]   grid 128
  gemm8<0, 128><<<(KD / 256) * (D / 128), 512, 98304, stream>>>(
      dicb, Wzb, Wz_b, nullptr, dzb, KD, D, E, 1.0f, 0);
  // 4) expS = exp(h . dz^T / 32) -> bf16 [16384,4096] grid 1024
  gemm8<1, 256><<<(M / 256) * (KD / 256), 512, 131072, stream>>>(
      h, dzb, nullptr, psum, S, M, KD, D, 0.03125f, 0);
  if (!fused_sum) {
    rowsum_bf16<<<M / 4, 256, 0, stream>>>((const unsigned short*)S, sums);
  }
  // 5+6) z = (expS . w3t^T) / rowsum -> f32 [16384,2048]  grid 512
  gemm8<2, 256><<<(M / 256) * (E / 256), 512, 131072, stream>>>(
      S, w3t, fused_sum ? psum : sums, nullptr, z, M, E, KD, 1.0f,
      fused_sum ? 16 : 1);
}

// Round 22
// 507.072 us; speedup vs baseline: 1.0208x; 1.0106x over previous
//
#include <hip/hip_runtime.h>
#include <hip/hip_bf16.h>
#include <stdint.h>

typedef __bf16 bf16;
typedef __bf16 bf16x4 __attribute__((ext_vector_type(4)));
typedef __bf16 bf16x8 __attribute__((ext_vector_type(8)));
typedef float f32x4 __attribute__((ext_vector_type(4)));
typedef unsigned short ushort8 __attribute__((ext_vector_type(8)));

// ---- async global->LDS, 16B per lane. LDS dest wave-uniform base; HW adds lane*16.
__device__ __forceinline__ void gload16(const bf16* g, char* l) {
  __builtin_amdgcn_global_load_lds(
      reinterpret_cast<const __attribute__((address_space(1))) unsigned int*>(
          reinterpret_cast<uintptr_t>(g)),
      reinterpret_cast<__attribute__((address_space(3))) unsigned int*>(
          reinterpret_cast<uintptr_t>(l)),
      16, 0, 0);
}

#define VMCNT(n)  asm volatile("s_waitcnt vmcnt(" #n ")" ::: "memory")
#define LGKM0()   do { asm volatile("s_waitcnt lgkmcnt(0)" ::: "memory"); \
                       __builtin_amdgcn_sched_barrier(0); } while (0)
#define BAR()     __builtin_amdgcn_s_barrier()

// ---- merged f32 -> bf16 cast over three regions (one launch) ----
__global__ __launch_bounds__(256) void cast3_bf16(
    const float* __restrict__ a, bf16* __restrict__ ao, int na,
    const float* __restrict__ b, bf16* __restrict__ bo, int nb,
    const float* __restrict__ c, bf16* __restrict__ co, int nc) {
  int i = blockIdx.x * blockDim.x + threadIdx.x;
  const int stride = gridDim.x * blockDim.x;
  const int tot = na + nb + nc;
  for (; i < tot; i += stride) {
    const float* src; bf16* dst; int j;
    if (i < na)            { src = a; dst = ao; j = i; }
    else if (i < na + nb)  { src = b; dst = bo; j = i - na; }
    else                   { src = c; dst = co; j = i - na - nb; }
    const float4 v0 = reinterpret_cast<const float4*>(src)[j * 2];
    const float4 v1 = reinterpret_cast<const float4*>(src)[j * 2 + 1];
    bf16x8 o = { (bf16)v0.x, (bf16)v0.y, (bf16)v0.z, (bf16)v0.w,
                 (bf16)v1.x, (bf16)v1.y, (bf16)v1.z, (bf16)v1.w };
    reinterpret_cast<bf16x8*>(dst)[j] = o;
  }
}

// ---- fallback rowsum of expS: one wave per row (4096 bf16), memory-bound ----
__global__ __launch_bounds__(256) void rowsum_bf16(const unsigned short* __restrict__ S,
                                                   float* __restrict__ sums) {
  const int row = blockIdx.x * 4 + (threadIdx.x >> 6);
  const int lane = threadIdx.x & 63;
  const unsigned short* r = S + (size_t)row * 4096;
  float s = 0.f;
#pragma unroll
  for (int i = 0; i < 8; ++i) {
    ushort8 v = *reinterpret_cast<const ushort8*>(r + i * 512 + lane * 8);
#pragma unroll
    for (int j = 0; j < 8; ++j) s += __uint_as_float(((unsigned)v[j]) << 16);
  }
#pragma unroll
  for (int o = 32; o; o >>= 1) s += __shfl_xor(s, o);
  if (lane == 0) sums[row] = s;
}

// ============ 8-phase NT GEMM body, MINIMAL-BARRIER wave-slip (R19/R21-verified) ============
// C[M,N] = op(A[M,K].B[N,K]^T).  BM=256, BK=64, 512 thr = 8 waves.
// BN==256: q1 {reads B+A01; stage A-lo(u+1); lgkm0; MFMA} (no barrier)
//          q2 {reads A23;   stage A-hi(u+1); lgkm0; MFMA} (no barrier)
//          q3 {BAR; reads A45; stage B-lo(u+2); lgkm0; MFMA}
//          q4 {reads A67; stage B-hi(u+2); vmcnt(4); lgkm0; MFMA; BAR}
// BN==128: q1 {reads bb+a01; stage A(u+1); lgkm0; MFMA} (no barrier)
//          q2 {BAR; reads a23; stage B(u+2); vmcnt(2); lgkm0; MFMA; BAR}
// Ledgers (R19/R21): BAR(q3 / q2-start) collectivizes earlier lgkm0 => B(u)-reads
// drained before stB(b,u+2).  END BAR collectivizes final lgkm0 (next stA(bn,u+1)
// safe) + counted vmcnt (FIFO => tile u+1 landed before its q1 reads).
// EPI: 0 = acc*scale+aux[col] (bf16) | 1 = exp(acc*scale) (bf16; no-max softmax,
// logits |max|~3.5 << 88; + optional row partials) | 2 = acc/rowsum (f32).
// Refactored to a __device__ body so independent GEMMs can share one dispatch.
template <int EPI, int BN>
__device__ __forceinline__ void gemm_body(
    const bf16* __restrict__ A, const bf16* __restrict__ B,
    const float* __restrict__ aux, float* __restrict__ psum,
    void* __restrict__ Cout, int M, int N, int K, float scale, int nparts,
    int orig, int nwg, char* lds) {
  constexpr int BUFSZ = 32768 + BN * 128;        // A 32KB + B
  constexpr int BOFF = 32768;
  constexpr int TM = (BN == 256) ? 128 : 64;
  constexpr int MI = TM / 16;
  constexpr int NI = 4;
  const int tid = threadIdx.x;
  const int lane = tid & 63, w = tid >> 6;

  // bijective XCD chunking (m204) over THIS problem's sub-grid, n-fast within chunk
  const int gridN = N / BN;
  int wgid;
  { const int q = nwg >> 3, r = nwg & 7, x = orig & 7, rest = orig >> 3;
    wgid = (x < r ? x * (q + 1) : r * (q + 1) + (x - r) * q) + rest; }
  const int m0 = (wgid / gridN) * 256;
  const int n0 = (wgid % gridN) * BN;

  // staging source: pre-swizzled chunk so linear LDS dest = swizzled layout
  const int srow = lane >> 3;                         // 0..7
  const int scol = ((lane & 7) ^ srow) * 8;           // chunk^row&7, elems
  const bf16* gA = A + (size_t)(m0 + w * 8 + srow) * K + scol;
  const bf16* gB = B + (size_t)(n0 + w * 8 + srow) * K + scol;

  auto stA = [&](char* dst, int u, int h) {
    gload16(gA + (size_t)(h * 128) * K + (size_t)u * 64, dst + h * 16384 + w * 1024);
    gload16(gA + (size_t)(h * 128 + 64) * K + (size_t)u * 64, dst + h * 16384 + 8192 + w * 1024);
  };
  auto stB = [&](char* dst, int u, int h) {
    gload16(gB + (size_t)(h * 128) * K + (size_t)u * 64, dst + BOFF + h * 16384 + w * 1024);
    gload16(gB + (size_t)(h * 128 + 64) * K + (size_t)u * 64, dst + BOFF + h * 16384 + 8192 + w * 1024);
  };

  // fragment read bases (swizzled)
  const int fr = lane & 15, hi = lane >> 4;
  int wm, wn;
  if constexpr (BN == 256) { wm = w >> 2; wn = w & 3; }
  else                     { wm = w >> 1; wn = w & 1; }
  const int abase = (wm * TM + fr) * 128 + ((hi ^ (fr & 7)) << 4);
  const int bbase = BOFF + (wn * 64 + fr) * 128 + ((hi ^ (fr & 7)) << 4);
#define RD_A(b, mi, ks) (*(const bf16x8*)((b) + ((abase + (mi) * 2048) ^ ((ks) << 6))))
#define RD_B(b, ni, ks) (*(const bf16x8*)((b) + ((bbase + (ni) * 2048) ^ ((ks) << 6))))

  f32x4 acc[MI][NI] = {};
  const int NT = K >> 6;

  // prologue: A(0), B(0), B(1); prove A(0)+B(0)
  stA(lds, 0, 0); stA(lds, 0, 1);
  stB(lds, 0, 0);
  if constexpr (BN == 256) stB(lds, 0, 1);
  stB(lds + BUFSZ, 1, 0);
  if constexpr (BN == 256) { stB(lds + BUFSZ, 1, 1); VMCNT(4); }
  else                     { VMCNT(2); }
  BAR();

  for (int u = 0; u < NT; ++u) {
    char* b  = lds + (size_t)(u & 1) * BUFSZ;
    char* bn = lds + (size_t)((u + 1) & 1) * BUFSZ;
    bf16x8 bb[2][NI], a[2][2];
    const bool sA = (u + 1) < NT, sB = (u + 2) < NT;

    if constexpr (BN == 256) {
      // ---- q1: B all + A(0,1); stage A-lo(u+1); lgkm0; MFMA  (no barrier) ----
      a[0][0] = RD_A(b, 0, 0); a[0][1] = RD_A(b, 0, 1);
      a[1][0] = RD_A(b, 1, 0); a[1][1] = RD_A(b, 1, 1);
#pragma unroll
      for (int ni = 0; ni < NI; ++ni) { bb[0][ni] = RD_B(b, ni, 0); bb[1][ni] = RD_B(b, ni, 1); }
      if (sA) stA(bn, u + 1, 0);
      LGKM0();
      __builtin_amdgcn_s_setprio(1);
#pragma unroll
      for (int m2 = 0; m2 < 2; ++m2)
#pragma unroll
        for (int ni = 0; ni < NI; ++ni) {
          acc[m2][ni] = __builtin_amdgcn_mfma_f32_16x16x32_bf16(a[m2][0], bb[0][ni], acc[m2][ni], 0, 0, 0);
          acc[m2][ni] = __builtin_amdgcn_mfma_f32_16x16x32_bf16(a[m2][1], bb[1][ni], acc[m2][ni], 0, 0, 0);
        }
      __builtin_amdgcn_s_setprio(0);
      // ---- q2: A(2,3); stage A-hi(u+1); lgkm0; MFMA  (no barrier) ----
      a[0][0] = RD_A(b, 2, 0); a[0][1] = RD_A(b, 2, 1);
      a[1][0] = RD_A(b, 3, 0); a[1][1] = RD_A(b, 3, 1);
      if (sA) stA(bn, u + 1, 1);
      LGKM0();
      __builtin_amdgcn_s_setprio(1);
#pragma unroll
      for (int m2 = 0; m2 < 2; ++m2)
#pragma unroll
        for (int ni = 0; ni < NI; ++ni) {
          acc[2 + m2][ni] = __builtin_amdgcn_mfma_f32_16x16x32_bf16(a[m2][0], bb[0][ni], acc[2 + m2][ni], 0, 0, 0);
          acc[2 + m2][ni] = __builtin_amdgcn_mfma_f32_16x16x32_bf16(a[m2][1], bb[1][ni], acc[2 + m2][ni], 0, 0, 0);
        }
      __builtin_amdgcn_s_setprio(0);
      // ---- q3: BAR (collectivizes q1/q2 drains); A(4,5); stage B-lo(u+2) ----
      BAR();
      a[0][0] = RD_A(b, 4, 0); a[0][1] = RD_A(b, 4, 1);
      a[1][0] = RD_A(b, 5, 0); a[1][1] = RD_A(b, 5, 1);
      if (sB) stB(b, u + 2, 0);
      LGKM0();
      __builtin_amdgcn_s_setprio(1);
#pragma unroll
      for (int m2 = 0; m2 < 2; ++m2)
#pragma unroll
        for (int ni = 0; ni < NI; ++ni) {
          acc[4 + m2][ni] = __builtin_amdgcn_mfma_f32_16x16x32_bf16(a[m2][0], bb[0][ni], acc[4 + m2][ni], 0, 0, 0);
          acc[4 + m2][ni] = __builtin_amdgcn_mfma_f32_16x16x32_bf16(a[m2][1], bb[1][ni], acc[4 + m2][ni], 0, 0, 0);
        }
      __builtin_amdgcn_s_setprio(0);
      // ---- q4: A(6,7); stage B-hi(u+2); vmcnt(4); lgkm0; MFMA; END BAR ----
      a[0][0] = RD_A(b, 6, 0); a[0][1] = RD_A(b, 6, 1);
      a[1][0] = RD_A(b, 7, 0); a[1][1] = RD_A(b, 7, 1);
      if (sB) stB(b, u + 2, 1);
      if (sB) VMCNT(4); else VMCNT(0);
      LGKM0();
      __builtin_amdgcn_s_setprio(1);
#pragma unroll
      for (int m2 = 0; m2 < 2; ++m2)
#pragma unroll
        for (int ni = 0; ni < NI; ++ni) {
          acc[6 + m2][ni] = __builtin_amdgcn_mfma_f32_16x16x32_bf16(a[m2][0], bb[0][ni], acc[6 + m2][ni], 0, 0, 0);
          acc[6 + m2][ni] = __builtin_amdgcn_mfma_f32_16x16x32_bf16(a[m2][1], bb[1][ni], acc[6 + m2][ni], 0, 0, 0);
        }
      __builtin_amdgcn_s_setprio(0);
      BAR();   // re-lockstep: collectivizes vmcnt(4) + lgkm0(q4)
    } else {
      // ---- BN==128 slip: q1 {reads; stage A(u+1); lgkm0; MFMA} no barrier ----
      a[0][0] = RD_A(b, 0, 0); a[0][1] = RD_A(b, 0, 1);
      a[1][0] = RD_A(b, 1, 0); a[1][1] = RD_A(b, 1, 1);
#pragma unroll
      for (int ni = 0; ni < NI; ++ni) { bb[0][ni] = RD_B(b, ni, 0); bb[1][ni] = RD_B(b, ni, 1); }
      if (sA) { stA(bn, u + 1, 0); stA(bn, u + 1, 1); }
      LGKM0();
      __builtin_amdgcn_s_setprio(1);
#pragma unroll
      for (int m2 = 0; m2 < 2; ++m2)
#pragma unroll
        for (int ni = 0; ni < NI; ++ni) {
          acc[m2][ni] = __builtin_amdgcn_mfma_f32_16x16x32_bf16(a[m2][0], bb[0][ni], acc[m2][ni], 0, 0, 0);
          acc[m2][ni] = __builtin_amdgcn_mfma_f32_16x16x32_bf16(a[m2][1], bb[1][ni], acc[m2][ni], 0, 0, 0);
        }
      __builtin_amdgcn_s_setprio(0);
      // ---- q2: BAR; a23; stage B(u+2); vmcnt(2); lgkm0; MFMA; BAR ----
      BAR();
      a[0][0] = RD_A(b, 2, 0); a[0][1] = RD_A(b, 2, 1);
      a[1][0] = RD_A(b, 3, 0); a[1][1] = RD_A(b, 3, 1);
      if (sB) stB(b, u + 2, 0);
      if (sB) VMCNT(2); else VMCNT(0);
      LGKM0();
      __builtin_amdgcn_s_setprio(1);
#pragma unroll
      for (int m2 = 0; m2 < 2; ++m2)
#pragma unroll
        for (int ni = 0; ni < NI; ++ni) {
          acc[2 + m2][ni] = __builtin_amdgcn_mfma_f32_16x16x32_bf16(a[m2][0], bb[0][ni], acc[2 + m2][ni], 0, 0, 0);
          acc[2 + m2][ni] = __builtin_amdgcn_mfma_f32_16x16x32_bf16(a[m2][1], bb[1][ni], acc[2 + m2][ni], 0, 0, 0);
        }
      __builtin_amdgcn_s_setprio(0);
      BAR();   // collectivizes vmcnt(2) + lgkm0(q2)
    }
  }
#undef RD_A
#undef RD_B

  // ---- EPI==2: gather this block's 256 row sums (nparts partials each) ----
  float* lsum = (float*)lds;
  if constexpr (EPI == 2) {
    if (tid < 256) {
      const float* p = aux + (size_t)(m0 + tid) * nparts;
      float s = 0.f;
      for (int bp = 0; bp < nparts; ++bp) s += p[bp];
      lsum[tid] = s;
    }
    __syncthreads();
  }

  // epilogue: C/D layout col = lane&15, row = (lane>>4)*4 + j  [m89-verified]
  const int lro = hi * 4;
  if constexpr (EPI == 2) {
#pragma unroll
    for (int mi = 0; mi < MI; ++mi)
#pragma unroll
      for (int j = 0; j < 4; ++j) {
        const int lr = wm * TM + mi * 16 + lro + j;
        const float inv = 1.0f / lsum[lr];   // same-addr across fr -> LDS broadcast
        const size_t grow = (size_t)(m0 + lr) * N;
#pragma unroll
        for (int ni = 0; ni < NI; ++ni)
          ((float*)Cout)[grow + n0 + wn * 64 + ni * 16 + fr] = acc[mi][ni][j] * inv;
      }
  } else {
    float rs[MI][4];
    if constexpr (EPI == 1) {
#pragma unroll
      for (int mi = 0; mi < MI; ++mi)
#pragma unroll
        for (int j = 0; j < 4; ++j) rs[mi][j] = 0.f;
    }
#pragma unroll
    for (int ni = 0; ni < NI; ++ni) {
      const int gcol = n0 + wn * 64 + ni * 16 + fr;
      float bvs = 0.f;
      if constexpr (EPI == 0) bvs = aux[gcol];
#pragma unroll
      for (int mi = 0; mi < MI; ++mi) {
        const int grow = m0 + wm * TM + mi * 16 + lro;
#pragma unroll
        for (int j = 0; j < 4; ++j) {
          float c = acc[mi][ni][j] * scale + bvs;
          if constexpr (EPI == 1) { c = __expf(c); rs[mi][j] += c; }
          ((bf16*)Cout)[(size_t)(grow + j) * N + gcol] = (bf16)c;
        }
      }
    }
    if constexpr (EPI == 1) {
      if (psum != nullptr) {
        float* wsum = (float*)lds;   // [4 wn][256 rows] = 4 KB (post-loop, LDS dead)
        __syncthreads();             // all waves exited K-loop before LDS reuse
#pragma unroll
        for (int mi = 0; mi < MI; ++mi)
#pragma unroll
          for (int j = 0; j < 4; ++j) {
            float s = rs[mi][j];
            s += __shfl_xor(s, 1); s += __shfl_xor(s, 2);
            s += __shfl_xor(s, 4); s += __shfl_xor(s, 8);
            if (fr == 0) wsum[wn * 256 + wm * TM + mi * 16 + lro + j] = s;
          }
        __syncthreads();
        if (tid < 256) {
          const float s = wsum[tid] + wsum[256 + tid] + wsum[512 + tid] + wsum[768 + tid];
          psum[(size_t)(m0 + tid) * 16 + (n0 >> 8)] = s;
        }
      }
    }
  }
}

template <int EPI, int BN>
__global__ __launch_bounds__(512, 2) void gemm8(
    const bf16* __restrict__ A, const bf16* __restrict__ B,
    const float* __restrict__ aux, float* __restrict__ psum,
    void* __restrict__ Cout, int M, int N, int K, float scale, int nparts) {
  extern __shared__ char lds[];
  gemm_body<EPI, BN>(A, B, aux, psum, Cout, M, N, K, scale, nparts,
                     blockIdx.x, gridDim.x, lds);
}

// ---- fused independent G2+G3 in one dispatch (fills the CUs G3 alone leaves idle) ----
__global__ __launch_bounds__(512, 2) void gemm_g23(
    const bf16* __restrict__ A2, const bf16* __restrict__ B2,
    const float* __restrict__ b2, bf16* __restrict__ C2,
    const bf16* __restrict__ A3, const bf16* __restrict__ B3,
    const float* __restrict__ b3, bf16* __restrict__ C3,
    int M, int D, int E, int KD, int g2n) {
  extern __shared__ char lds[];
  if ((int)blockIdx.x < g2n)
    gemm_body<0, 256>(A2, B2, b2, nullptr, C2, M, D, D, 1.0f, 0,
                      blockIdx.x, g2n, lds);
  else
    gemm_body<0, 128>(A3, B3, b3, nullptr, C3, KD, D, E, 1.0f, 0,
                      blockIdx.x - g2n, gridDim.x - g2n, lds);
}

// ------- prep: dicb[k,e] = bf16(dic[k,e])  AND  w3t[e,k] = bf16(prior[k]*dic[k,e]) -------
__global__ __launch_bounds__(256) void prep_dic(const float* __restrict__ dic,
                                                const float* __restrict__ prior,
                                                bf16* __restrict__ dicb,
                                                bf16* __restrict__ w3t) {
  const int KD = 4096, E = 2048;
  __shared__ bf16 t[64][72];
  const int k0 = blockIdx.x * 64, e0 = blockIdx.y * 64;
  const int tid = threadIdx.x;
  const int er = (tid & 15) * 4;
  const int kr = tid >> 4;
#pragma unroll
  for (int p = 0; p < 4; ++p) {
    const int k = kr + p * 16;
    const float pr = prior[k0 + k];
    const float4 v = *reinterpret_cast<const float4*>(dic + (size_t)(k0 + k) * E + e0 + er);
    bf16x4 db = { (bf16)v.x, (bf16)v.y, (bf16)v.z, (bf16)v.w };
    *reinterpret_cast<bf16x4*>(dicb + (size_t)(k0 + k) * E + e0 + er) = db;
    t[er + 0][k] = (bf16)(v.x * pr);
    t[er + 1][k] = (bf16)(v.y * pr);
    t[er + 2][k] = (bf16)(v.z * pr);
    t[er + 3][k] = (bf16)(v.w * pr);
  }
  __syncthreads();
  const int e = tid >> 2, kc = (tid & 3) * 16;
  ushort8 a = *reinterpret_cast<ushort8*>(&t[e][kc]);
  ushort8 b = *reinterpret_cast<ushort8*>(&t[e][kc + 8]);
  unsigned short* dst = (unsigned short*)w3t + (size_t)(e0 + e) * KD + k0 + kc;
  *reinterpret_cast<ushort8*>(dst) = a;
  *reinterpret_cast<ushort8*>(dst + 8) = b;
}

extern "C" void kernel_launch(void* const* d_in, const int* in_sizes, int n_in,
                              void* d_out, int out_size, void* d_ws, size_t ws_size,
                              hipStream_t stream) {
  const float* y     = (const float*)d_in[0];  // [16384,1024]
  const float* Wy_w  = (const float*)d_in[1];  // [1024,1024]
  const float* Wy_b  = (const float*)d_in[2];  // [1024]
  const float* Wz_w  = (const float*)d_in[3];  // [1024,2048]
  const float* Wz_b  = (const float*)d_in[4];  // [1024]
  const float* dic   = (const float*)d_in[5];  // [4096,2048]
  const float* prior = (const float*)d_in[6];  // [4096]
  float* z = (float*)d_out;                    // [16384,2048]

  const int M = 16384, D = 1024, E = 2048, KD = 4096;

  char* ws = (char*)d_ws;
  bf16* w3t  = (bf16*)(ws);                        // [0, 16M)
  bf16* h    = (bf16*)(ws + ((size_t)16 << 20));   // [16M, 48M)
  bf16* dzb  = (bf16*)(ws + ((size_t)48 << 20));   // [48M, 56M)
  bf16* S    = (bf16*)(ws + ((size_t)56 << 20));   // [56M, 184M)  expS after G4
  bf16* yb   = (bf16*)(ws + ((size_t)56 << 20));   // cast overlays inside S (dead pre-G4)
  bf16* Wyb  = (bf16*)(ws + ((size_t)88 << 20));
  bf16* Wzb  = (bf16*)(ws + ((size_t)90 << 20));
  bf16* dicb = (bf16*)(ws + ((size_t)94 << 20));

  // psum TAIL slab [184M, 185M): outside every live region during G4.
  const bool fused_sum = ws_size >= ((size_t)185 << 20);
  float* psum = fused_sum ? (float*)(ws + ((size_t)184 << 20)) : nullptr;
  float* sums = (float*)(ws + ((size_t)16 << 20));  // fallback: h region, dead after G4

  // 0) pre-cast f32 operands to bf16 in ONE launch (dic cast fused into prep_dic)
  cast3_bf16<<<2048, 256, 0, stream>>>(y, yb, M * D / 8,
                                       Wy_w, Wyb, D * D / 8,
                                       Wz_w, Wzb, D * E / 8);
  // 1) dicb + w3t from one read of dic
  prep_dic<<<dim3(KD / 64, E / 64), 256, 0, stream>>>(dic, prior, dicb, w3t);
  // 2+3) h = yb.Wyb^T + Wy_b (grid 256, BN=256)  ||  dz = dicb.Wzb^T + Wz_b
  //      (grid 128, BN=128) -- independent, fused into one 384-block dispatch
  {
    const int g2n = (M / 256) * (D / 256);            // 256
    const int g3n = (KD / 256) * (D / 128);           // 128
    gemm_g23<<<g2n + g3n, 512, 131072, stream>>>(
        yb, Wyb, Wy_b, h, dicb, Wzb, Wz_b, dzb, M, D, E, KD, g2n);
  }
  // 4) expS = exp(h . dz^T / 32) -> bf16 [16384,4096] grid 1024
  gemm8<1, 256><<<(M / 256) * (KD / 256), 512, 131072, stream>>>(
      h, dzb, nullptr, psum, S, M, KD, D, 0.03125f, 0);
  if (!fused_sum) {
    rowsum_bf16<<<M / 4, 256, 0, stream>>>((const unsigned short*)S, sums);
  }
  // 5+6) z = (expS . w3t^T) / rowsum -> f32 [16384,2048]  grid 512
  gemm8<2, 256><<<(M / 256) * (E / 256), 512, 131072, stream>>>(
      S, w3t, fused_sum ? psum : sums, nullptr, z, M, E, KD, 1.0f,
      fused_sum ? 16 : 1);
}

// Round 23
// 504.935 us; speedup vs baseline: 1.0251x; 1.0042x over previous
//
#include <hip/hip_runtime.h>
#include <hip/hip_bf16.h>
#include <stdint.h>

typedef __bf16 bf16;
typedef __bf16 bf16x4 __attribute__((ext_vector_type(4)));
typedef __bf16 bf16x8 __attribute__((ext_vector_type(8)));
typedef float f32x4 __attribute__((ext_vector_type(4)));
typedef unsigned short ushort8 __attribute__((ext_vector_type(8)));

// ---- async global->LDS, 16B per lane. LDS dest wave-uniform base; HW adds lane*16.
__device__ __forceinline__ void gload16(const bf16* g, char* l) {
  __builtin_amdgcn_global_load_lds(
      reinterpret_cast<const __attribute__((address_space(1))) unsigned int*>(
          reinterpret_cast<uintptr_t>(g)),
      reinterpret_cast<__attribute__((address_space(3))) unsigned int*>(
          reinterpret_cast<uintptr_t>(l)),
      16, 0, 0);
}

#define VMCNT(n)  asm volatile("s_waitcnt vmcnt(" #n ")" ::: "memory")
#define LGKM0()   do { asm volatile("s_waitcnt lgkmcnt(0)" ::: "memory"); \
                       __builtin_amdgcn_sched_barrier(0); } while (0)
#define BAR()     __builtin_amdgcn_s_barrier()

// ==== merged prep: blocks [0,CAST_B) cast y/Wy/Wz to bf16; blocks [CAST_B, +2048)
// ==== do the dic pass (dicb = bf16(dic), w3t[e,k] = bf16(prior[k]*dic[k,e])).
// Independent memory-bound halves, disjoint outputs -> one dispatch fills the GPU.
#define CAST_B 2048
__global__ __launch_bounds__(256) void prep_all(
    const float* __restrict__ y, bf16* __restrict__ yo, int na,
    const float* __restrict__ wy, bf16* __restrict__ wyo, int nb,
    const float* __restrict__ wz, bf16* __restrict__ wzo, int nc,
    const float* __restrict__ dic, const float* __restrict__ prior,
    bf16* __restrict__ dicb, bf16* __restrict__ w3t) {
  __shared__ bf16 t[64][72];
  const int tid = threadIdx.x;
  if ((int)blockIdx.x < CAST_B) {
    int i = blockIdx.x * 256 + tid;
    const int stride = CAST_B * 256;
    const int tot = na + nb + nc;
    for (; i < tot; i += stride) {
      const float* src; bf16* dst; int j;
      if (i < na)            { src = y;  dst = yo;  j = i; }
      else if (i < na + nb)  { src = wy; dst = wyo; j = i - na; }
      else                   { src = wz; dst = wzo; j = i - na - nb; }
      const float4 v0 = reinterpret_cast<const float4*>(src)[j * 2];
      const float4 v1 = reinterpret_cast<const float4*>(src)[j * 2 + 1];
      bf16x8 o = { (bf16)v0.x, (bf16)v0.y, (bf16)v0.z, (bf16)v0.w,
                   (bf16)v1.x, (bf16)v1.y, (bf16)v1.z, (bf16)v1.w };
      reinterpret_cast<bf16x8*>(dst)[j] = o;
    }
  } else {
    const int KD = 4096, E = 2048;
    const int b2 = blockIdx.x - CAST_B;            // 0..2047
    const int k0 = (b2 & 63) * 64, e0 = (b2 >> 6) * 64;
    const int er = (tid & 15) * 4;
    const int kr = tid >> 4;
#pragma unroll
    for (int p = 0; p < 4; ++p) {
      const int k = kr + p * 16;
      const float pr = prior[k0 + k];
      const float4 v = *reinterpret_cast<const float4*>(dic + (size_t)(k0 + k) * E + e0 + er);
      bf16x4 db = { (bf16)v.x, (bf16)v.y, (bf16)v.z, (bf16)v.w };
      *reinterpret_cast<bf16x4*>(dicb + (size_t)(k0 + k) * E + e0 + er) = db;
      t[er + 0][k] = (bf16)(v.x * pr);
      t[er + 1][k] = (bf16)(v.y * pr);
      t[er + 2][k] = (bf16)(v.z * pr);
      t[er + 3][k] = (bf16)(v.w * pr);
    }
    __syncthreads();
    const int e = tid >> 2, kc = (tid & 3) * 16;
    ushort8 a = *reinterpret_cast<ushort8*>(&t[e][kc]);
    ushort8 b = *reinterpret_cast<ushort8*>(&t[e][kc + 8]);
    unsigned short* dst = (unsigned short*)w3t + (size_t)(e0 + e) * KD + k0 + kc;
    *reinterpret_cast<ushort8*>(dst) = a;
    *reinterpret_cast<ushort8*>(dst + 8) = b;
  }
}

// ---- fallback rowsum of expS: one wave per row (4096 bf16), memory-bound ----
__global__ __launch_bounds__(256) void rowsum_bf16(const unsigned short* __restrict__ S,
                                                   float* __restrict__ sums) {
  const int row = blockIdx.x * 4 + (threadIdx.x >> 6);
  const int lane = threadIdx.x & 63;
  const unsigned short* r = S + (size_t)row * 4096;
  float s = 0.f;
#pragma unroll
  for (int i = 0; i < 8; ++i) {
    ushort8 v = *reinterpret_cast<const ushort8*>(r + i * 512 + lane * 8);
#pragma unroll
    for (int j = 0; j < 8; ++j) s += __uint_as_float(((unsigned)v[j]) << 16);
  }
#pragma unroll
  for (int o = 32; o; o >>= 1) s += __shfl_xor(s, o);
  if (lane == 0) sums[row] = s;
}

// ============ 8-phase NT GEMM body, MINIMAL-BARRIER wave-slip (R19/R21-verified) ============
// C[M,N] = op(A[M,K].B[N,K]^T).  BM=256, BK=64, 512 thr = 8 waves.
// BN==256: q1 {reads B+A01; stage A-lo(u+1); lgkm0; MFMA} (no barrier)
//          q2 {reads A23;   stage A-hi(u+1); lgkm0; MFMA} (no barrier)
//          q3 {BAR; reads A45; stage B-lo(u+2); lgkm0; MFMA}
//          q4 {reads A67; stage B-hi(u+2); vmcnt(4); lgkm0; MFMA; BAR}
// BN==128: q1 {reads bb+a01; stage A(u+1); lgkm0; MFMA} (no barrier)
//          q2 {BAR; reads a23; stage B(u+2); vmcnt(2); lgkm0; MFMA; BAR}
// Ledgers (R19/R21): BAR(q3 / q2-start) collectivizes earlier lgkm0 => B(u)-reads
// drained before stB(b,u+2).  END BAR collectivizes final lgkm0 (next stA(bn,u+1)
// safe) + counted vmcnt (FIFO => tile u+1 landed before its q1 reads).
// EPI: 0 = acc*scale+aux[col] (bf16) | 1 = exp(acc*scale) (bf16; no-max softmax,
// logits |max|~3.5 << 88; + optional row partials) | 2 = acc/rowsum (f32).
template <int EPI, int BN>
__device__ __forceinline__ void gemm_body(
    const bf16* __restrict__ A, const bf16* __restrict__ B,
    const float* __restrict__ aux, float* __restrict__ psum,
    void* __restrict__ Cout, int M, int N, int K, float scale, int nparts,
    int orig, int nwg, char* lds) {
  constexpr int BUFSZ = 32768 + BN * 128;        // A 32KB + B
  constexpr int BOFF = 32768;
  constexpr int TM = (BN == 256) ? 128 : 64;
  constexpr int MI = TM / 16;
  constexpr int NI = 4;
  const int tid = threadIdx.x;
  const int lane = tid & 63, w = tid >> 6;

  // bijective XCD chunking (m204) over THIS problem's sub-grid, n-fast within chunk
  const int gridN = N / BN;
  int wgid;
  { const int q = nwg >> 3, r = nwg & 7, x = orig & 7, rest = orig >> 3;
    wgid = (x < r ? x * (q + 1) : r * (q + 1) + (x - r) * q) + rest; }
  const int m0 = (wgid / gridN) * 256;
  const int n0 = (wgid % gridN) * BN;

  // staging source: pre-swizzled chunk so linear LDS dest = swizzled layout
  const int srow = lane >> 3;                         // 0..7
  const int scol = ((lane & 7) ^ srow) * 8;           // chunk^row&7, elems
  const bf16* gA = A + (size_t)(m0 + w * 8 + srow) * K + scol;
  const bf16* gB = B + (size_t)(n0 + w * 8 + srow) * K + scol;

  auto stA = [&](char* dst, int u, int h) {
    gload16(gA + (size_t)(h * 128) * K + (size_t)u * 64, dst + h * 16384 + w * 1024);
    gload16(gA + (size_t)(h * 128 + 64) * K + (size_t)u * 64, dst + h * 16384 + 8192 + w * 1024);
  };
  auto stB = [&](char* dst, int u, int h) {
    gload16(gB + (size_t)(h * 128) * K + (size_t)u * 64, dst + BOFF + h * 16384 + w * 1024);
    gload16(gB + (size_t)(h * 128 + 64) * K + (size_t)u * 64, dst + BOFF + h * 16384 + 8192 + w * 1024);
  };

  // fragment read bases (swizzled)
  const int fr = lane & 15, hi = lane >> 4;
  int wm, wn;
  if constexpr (BN == 256) { wm = w >> 2; wn = w & 3; }
  else                     { wm = w >> 1; wn = w & 1; }
  const int abase = (wm * TM + fr) * 128 + ((hi ^ (fr & 7)) << 4);
  const int bbase = BOFF + (wn * 64 + fr) * 128 + ((hi ^ (fr & 7)) << 4);
#define RD_A(b, mi, ks) (*(const bf16x8*)((b) + ((abase + (mi) * 2048) ^ ((ks) << 6))))
#define RD_B(b, ni, ks) (*(const bf16x8*)((b) + ((bbase + (ni) * 2048) ^ ((ks) << 6))))

  f32x4 acc[MI][NI] = {};
  const int NT = K >> 6;

  // prologue: A(0), B(0), B(1); prove A(0)+B(0)
  stA(lds, 0, 0); stA(lds, 0, 1);
  stB(lds, 0, 0);
  if constexpr (BN == 256) stB(lds, 0, 1);
  stB(lds + BUFSZ, 1, 0);
  if constexpr (BN == 256) { stB(lds + BUFSZ, 1, 1); VMCNT(4); }
  else                     { VMCNT(2); }
  BAR();

  for (int u = 0; u < NT; ++u) {
    char* b  = lds + (size_t)(u & 1) * BUFSZ;
    char* bn = lds + (size_t)((u + 1) & 1) * BUFSZ;
    bf16x8 bb[2][NI], a[2][2];
    const bool sA = (u + 1) < NT, sB = (u + 2) < NT;

    if constexpr (BN == 256) {
      // ---- q1: B all + A(0,1); stage A-lo(u+1); lgkm0; MFMA  (no barrier) ----
      a[0][0] = RD_A(b, 0, 0); a[0][1] = RD_A(b, 0, 1);
      a[1][0] = RD_A(b, 1, 0); a[1][1] = RD_A(b, 1, 1);
#pragma unroll
      for (int ni = 0; ni < NI; ++ni) { bb[0][ni] = RD_B(b, ni, 0); bb[1][ni] = RD_B(b, ni, 1); }
      if (sA) stA(bn, u + 1, 0);
      LGKM0();
      __builtin_amdgcn_s_setprio(1);
#pragma unroll
      for (int m2 = 0; m2 < 2; ++m2)
#pragma unroll
        for (int ni = 0; ni < NI; ++ni) {
          acc[m2][ni] = __builtin_amdgcn_mfma_f32_16x16x32_bf16(a[m2][0], bb[0][ni], acc[m2][ni], 0, 0, 0);
          acc[m2][ni] = __builtin_amdgcn_mfma_f32_16x16x32_bf16(a[m2][1], bb[1][ni], acc[m2][ni], 0, 0, 0);
        }
      __builtin_amdgcn_s_setprio(0);
      // ---- q2: A(2,3); stage A-hi(u+1); lgkm0; MFMA  (no barrier) ----
      a[0][0] = RD_A(b, 2, 0); a[0][1] = RD_A(b, 2, 1);
      a[1][0] = RD_A(b, 3, 0); a[1][1] = RD_A(b, 3, 1);
      if (sA) stA(bn, u + 1, 1);
      LGKM0();
      __builtin_amdgcn_s_setprio(1);
#pragma unroll
      for (int m2 = 0; m2 < 2; ++m2)
#pragma unroll
        for (int ni = 0; ni < NI; ++ni) {
          acc[2 + m2][ni] = __builtin_amdgcn_mfma_f32_16x16x32_bf16(a[m2][0], bb[0][ni], acc[2 + m2][ni], 0, 0, 0);
          acc[2 + m2][ni] = __builtin_amdgcn_mfma_f32_16x16x32_bf16(a[m2][1], bb[1][ni], acc[2 + m2][ni], 0, 0, 0);
        }
      __builtin_amdgcn_s_setprio(0);
      // ---- q3: BAR (collectivizes q1/q2 drains); A(4,5); stage B-lo(u+2) ----
      BAR();
      a[0][0] = RD_A(b, 4, 0); a[0][1] = RD_A(b, 4, 1);
      a[1][0] = RD_A(b, 5, 0); a[1][1] = RD_A(b, 5, 1);
      if (sB) stB(b, u + 2, 0);
      LGKM0();
      __builtin_amdgcn_s_setprio(1);
#pragma unroll
      for (int m2 = 0; m2 < 2; ++m2)
#pragma unroll
        for (int ni = 0; ni < NI; ++ni) {
          acc[4 + m2][ni] = __builtin_amdgcn_mfma_f32_16x16x32_bf16(a[m2][0], bb[0][ni], acc[4 + m2][ni], 0, 0, 0);
          acc[4 + m2][ni] = __builtin_amdgcn_mfma_f32_16x16x32_bf16(a[m2][1], bb[1][ni], acc[4 + m2][ni], 0, 0, 0);
        }
      __builtin_amdgcn_s_setprio(0);
      // ---- q4: A(6,7); stage B-hi(u+2); vmcnt(4); lgkm0; MFMA; END BAR ----
      a[0][0] = RD_A(b, 6, 0); a[0][1] = RD_A(b, 6, 1);
      a[1][0] = RD_A(b, 7, 0); a[1][1] = RD_A(b, 7, 1);
      if (sB) stB(b, u + 2, 1);
      if (sB) VMCNT(4); else VMCNT(0);
      LGKM0();
      __builtin_amdgcn_s_setprio(1);
#pragma unroll
      for (int m2 = 0; m2 < 2; ++m2)
#pragma unroll
        for (int ni = 0; ni < NI; ++ni) {
          acc[6 + m2][ni] = __builtin_amdgcn_mfma_f32_16x16x32_bf16(a[m2][0], bb[0][ni], acc[6 + m2][ni], 0, 0, 0);
          acc[6 + m2][ni] = __builtin_amdgcn_mfma_f32_16x16x32_bf16(a[m2][1], bb[1][ni], acc[6 + m2][ni], 0, 0, 0);
        }
      __builtin_amdgcn_s_setprio(0);
      BAR();   // re-lockstep: collectivizes vmcnt(4) + lgkm0(q4)
    } else {
      // ---- BN==128 slip: q1 {reads; stage A(u+1); lgkm0; MFMA} no barrier ----
      a[0][0] = RD_A(b, 0, 0); a[0][1] = RD_A(b, 0, 1);
      a[1][0] = RD_A(b, 1, 0); a[1][1] = RD_A(b, 1, 1);
#pragma unroll
      for (int ni = 0; ni < NI; ++ni) { bb[0][ni] = RD_B(b, ni, 0); bb[1][ni] = RD_B(b, ni, 1); }
      if (sA) { stA(bn, u + 1, 0); stA(bn, u + 1, 1); }
      LGKM0();
      __builtin_amdgcn_s_setprio(1);
#pragma unroll
      for (int m2 = 0; m2 < 2; ++m2)
#pragma unroll
        for (int ni = 0; ni < NI; ++ni) {
          acc[m2][ni] = __builtin_amdgcn_mfma_f32_16x16x32_bf16(a[m2][0], bb[0][ni], acc[m2][ni], 0, 0, 0);
          acc[m2][ni] = __builtin_amdgcn_mfma_f32_16x16x32_bf16(a[m2][1], bb[1][ni], acc[m2][ni], 0, 0, 0);
        }
      __builtin_amdgcn_s_setprio(0);
      // ---- q2: BAR; a23; stage B(u+2); vmcnt(2); lgkm0; MFMA; BAR ----
      BAR();
      a[0][0] = RD_A(b, 2, 0); a[0][1] = RD_A(b, 2, 1);
      a[1][0] = RD_A(b, 3, 0); a[1][1] = RD_A(b, 3, 1);
      if (sB) stB(b, u + 2, 0);
      if (sB) VMCNT(2); else VMCNT(0);
      LGKM0();
      __builtin_amdgcn_s_setprio(1);
#pragma unroll
      for (int m2 = 0; m2 < 2; ++m2)
#pragma unroll
        for (int ni = 0; ni < NI; ++ni) {
          acc[2 + m2][ni] = __builtin_amdgcn_mfma_f32_16x16x32_bf16(a[m2][0], bb[0][ni], acc[2 + m2][ni], 0, 0, 0);
          acc[2 + m2][ni] = __builtin_amdgcn_mfma_f32_16x16x32_bf16(a[m2][1], bb[1][ni], acc[2 + m2][ni], 0, 0, 0);
        }
      __builtin_amdgcn_s_setprio(0);
      BAR();   // collectivizes vmcnt(2) + lgkm0(q2)
    }
  }
#undef RD_A
#undef RD_B

  // ---- EPI==2: gather this block's 256 row sums (nparts partials each) ----
  float* lsum = (float*)lds;
  if constexpr (EPI == 2) {
    if (tid < 256) {
      const float* p = aux + (size_t)(m0 + tid) * nparts;
      float s = 0.f;
      for (int bp = 0; bp < nparts; ++bp) s += p[bp];
      lsum[tid] = s;
    }
    __syncthreads();
  }

  // epilogue: C/D layout col = lane&15, row = (lane>>4)*4 + j  [m89-verified]
  const int lro = hi * 4;
  if constexpr (EPI == 2) {
#pragma unroll
    for (int mi = 0; mi < MI; ++mi)
#pragma unroll
      for (int j = 0; j < 4; ++j) {
        const int lr = wm * TM + mi * 16 + lro + j;
        const float inv = 1.0f / lsum[lr];   // same-addr across fr -> LDS broadcast
        const size_t grow = (size_t)(m0 + lr) * N;
#pragma unroll
        for (int ni = 0; ni < NI; ++ni)
          ((float*)Cout)[grow + n0 + wn * 64 + ni * 16 + fr] = acc[mi][ni][j] * inv;
      }
  } else {
    float rs[MI][4];
    if constexpr (EPI == 1) {
#pragma unroll
      for (int mi = 0; mi < MI; ++mi)
#pragma unroll
        for (int j = 0; j < 4; ++j) rs[mi][j] = 0.f;
    }
#pragma unroll
    for (int ni = 0; ni < NI; ++ni) {
      const int gcol = n0 + wn * 64 + ni * 16 + fr;
      float bvs = 0.f;
      if constexpr (EPI == 0) bvs = aux[gcol];
#pragma unroll
      for (int mi = 0; mi < MI; ++mi) {
        const int grow = m0 + wm * TM + mi * 16 + lro;
#pragma unroll
        for (int j = 0; j < 4; ++j) {
          float c = acc[mi][ni][j] * scale + bvs;
          if constexpr (EPI == 1) { c = __expf(c); rs[mi][j] += c; }
          ((bf16*)Cout)[(size_t)(grow + j) * N + gcol] = (bf16)c;
        }
      }
    }
    if constexpr (EPI == 1) {
      if (psum != nullptr) {
        float* wsum = (float*)lds;   // [4 wn][256 rows] = 4 KB (post-loop, LDS dead)
        __syncthreads();             // all waves exited K-loop before LDS reuse
#pragma unroll
        for (int mi = 0; mi < MI; ++mi)
#pragma unroll
          for (int j = 0; j < 4; ++j) {
            float s = rs[mi][j];
            s += __shfl_xor(s, 1); s += __shfl_xor(s, 2);
            s += __shfl_xor(s, 4); s += __shfl_xor(s, 8);
            if (fr == 0) wsum[wn * 256 + wm * TM + mi * 16 + lro + j] = s;
          }
        __syncthreads();
        if (tid < 256) {
          const float s = wsum[tid] + wsum[256 + tid] + wsum[512 + tid] + wsum[768 + tid];
          psum[(size_t)(m0 + tid) * 16 + (n0 >> 8)] = s;
        }
      }
    }
  }
}

template <int EPI, int BN>
__global__ __launch_bounds__(512, 2) void gemm8(
    const bf16* __restrict__ A, const bf16* __restrict__ B,
    const float* __restrict__ aux, float* __restrict__ psum,
    void* __restrict__ Cout, int M, int N, int K, float scale, int nparts) {
  extern __shared__ char lds[];
  gemm_body<EPI, BN>(A, B, aux, psum, Cout, M, N, K, scale, nparts,
                     blockIdx.x, gridDim.x, lds);
}

// ---- fused independent G2+G3 in one dispatch (fills the CUs G3 alone leaves idle) ----
__global__ __launch_bounds__(512, 2) void gemm_g23(
    const bf16* __restrict__ A2, const bf16* __restrict__ B2,
    const float* __restrict__ b2, bf16* __restrict__ C2,
    const bf16* __restrict__ A3, const bf16* __restrict__ B3,
    const float* __restrict__ b3, bf16* __restrict__ C3,
    int M, int D, int E, int KD, int g2n) {
  extern __shared__ char lds[];
  if ((int)blockIdx.x < g2n)
    gemm_body<0, 256>(A2, B2, b2, nullptr, C2, M, D, D, 1.0f, 0,
                      blockIdx.x, g2n, lds);
  else
    gemm_body<0, 128>(A3, B3, b3, nullptr, C3, KD, D, E, 1.0f, 0,
                      blockIdx.x - g2n, gridDim.x - g2n, lds);
}

extern "C" void kernel_launch(void* const* d_in, const int* in_sizes, int n_in,
                              void* d_out, int out_size, void* d_ws, size_t ws_size,
                              hipStream_t stream) {
  const float* y     = (const float*)d_in[0];  // [16384,1024]
  const float* Wy_w  = (const float*)d_in[1];  // [1024,1024]
  const float* Wy_b  = (const float*)d_in[2];  // [1024]
  const float* Wz_w  = (const float*)d_in[3];  // [1024,2048]
  const float* Wz_b  = (const float*)d_in[4];  // [1024]
  const float* dic   = (const float*)d_in[5];  // [4096,2048]
  const float* prior = (const float*)d_in[6];  // [4096]
  float* z = (float*)d_out;                    // [16384,2048]

  const int M = 16384, D = 1024, E = 2048, KD = 4096;

  char* ws = (char*)d_ws;
  bf16* w3t  = (bf16*)(ws);                        // [0, 16M)
  bf16* h    = (bf16*)(ws + ((size_t)16 << 20));   // [16M, 48M)
  bf16* dzb  = (bf16*)(ws + ((size_t)48 << 20));   // [48M, 56M)
  bf16* S    = (bf16*)(ws + ((size_t)56 << 20));   // [56M, 184M)  expS after G4
  bf16* yb   = (bf16*)(ws + ((size_t)56 << 20));   // cast overlays inside S (dead pre-G4)
  bf16* Wyb  = (bf16*)(ws + ((size_t)88 << 20));
  bf16* Wzb  = (bf16*)(ws + ((size_t)90 << 20));
  bf16* dicb = (bf16*)(ws + ((size_t)94 << 20));

  // psum TAIL slab [184M, 185M): outside every live region during G4.
  const bool fused_sum = ws_size >= ((size_t)185 << 20);
  float* psum = fused_sum ? (float*)(ws + ((size_t)184 << 20)) : nullptr;
  float* sums = (float*)(ws + ((size_t)16 << 20));  // fallback: h region, dead after G4

  // 0+1) all casts + dic pass in ONE 4096-block dispatch
  prep_all<<<CAST_B + 2048, 256, 0, stream>>>(
      y, yb, M * D / 8, Wy_w, Wyb, D * D / 8, Wz_w, Wzb, D * E / 8,
      dic, prior, dicb, w3t);
  // 2+3) h = yb.Wyb^T + Wy_b (grid 256, BN=256)  ||  dz = dicb.Wzb^T + Wz_b
  //      (grid 128, BN=128) -- independent, fused into one 384-block dispatch
  {
    const int g2n = (M / 256) * (D / 256);            // 256
    const int g3n = (KD / 256) * (D / 128);           // 128
    gemm_g23<<<g2n + g3n, 512, 131072, stream>>>(
        yb, Wyb, Wy_b, h, dicb, Wzb, Wz_b, dzb, M, D, E, KD, g2n);
  }
  // 4) expS = exp(h . dz^T / 32) -> bf16 [16384,4096] grid 1024
  gemm8<1, 256><<<(M / 256) * (KD / 256), 512, 131072, stream>>>(
      h, dzb, nullptr, psum, S, M, KD, D, 0.03125f, 0);
  if (!fused_sum) {
    rowsum_bf16<<<M / 4, 256, 0, stream>>>((const unsigned short*)S, sums);
  }
  // 5+6) z = (expS . w3t^T) / rowsum -> f32 [16384,2048]  grid 512
  gemm8<2, 256><<<(M / 256) * (E / 256), 512, 131072, stream>>>(
      S, w3t, fused_sum ? psum : sums, nullptr, z, M, E, KD, 1.0f,
      fused_sum ? 16 : 1);
}

// Round 24
// 490.351 us; speedup vs baseline: 1.0556x; 1.0297x over previous
//
#include <hip/hip_runtime.h>
#include <hip/hip_bf16.h>
#include <stdint.h>

typedef __bf16 bf16;
typedef __bf16 bf16x4 __attribute__((ext_vector_type(4)));
typedef __bf16 bf16x8 __attribute__((ext_vector_type(8)));
typedef float f32x4 __attribute__((ext_vector_type(4)));
typedef unsigned short ushort8 __attribute__((ext_vector_type(8)));

// ---- async global->LDS, 16B per lane. LDS dest wave-uniform base; HW adds lane*16.
__device__ __forceinline__ void gload16(const bf16* g, char* l) {
  __builtin_amdgcn_global_load_lds(
      reinterpret_cast<const __attribute__((address_space(1))) unsigned int*>(
          reinterpret_cast<uintptr_t>(g)),
      reinterpret_cast<__attribute__((address_space(3))) unsigned int*>(
          reinterpret_cast<uintptr_t>(l)),
      16, 0, 0);
}

#define VMCNT(n)  asm volatile("s_waitcnt vmcnt(" #n ")" ::: "memory")
#define LGKM0()   do { asm volatile("s_waitcnt lgkmcnt(0)" ::: "memory"); \
                       __builtin_amdgcn_sched_barrier(0); } while (0)
#define BAR()     __builtin_amdgcn_s_barrier()

// ==== merged prep: blocks [0,CAST_B) cast y/Wy/Wz to bf16; blocks [CAST_B, +2048)
// ==== do the dic pass (dicb = bf16(dic), w3t[e,k] = bf16(prior[k]*dic[k,e])).
#define CAST_B 2048
__global__ __launch_bounds__(256) void prep_all(
    const float* __restrict__ y, bf16* __restrict__ yo, int na,
    const float* __restrict__ wy, bf16* __restrict__ wyo, int nb,
    const float* __restrict__ wz, bf16* __restrict__ wzo, int nc,
    const float* __restrict__ dic, const float* __restrict__ prior,
    bf16* __restrict__ dicb, bf16* __restrict__ w3t) {
  __shared__ bf16 t[64][72];
  const int tid = threadIdx.x;
  if ((int)blockIdx.x < CAST_B) {
    int i = blockIdx.x * 256 + tid;
    const int stride = CAST_B * 256;
    const int tot = na + nb + nc;
    for (; i < tot; i += stride) {
      const float* src; bf16* dst; int j;
      if (i < na)            { src = y;  dst = yo;  j = i; }
      else if (i < na + nb)  { src = wy; dst = wyo; j = i - na; }
      else                   { src = wz; dst = wzo; j = i - na - nb; }
      const float4 v0 = reinterpret_cast<const float4*>(src)[j * 2];
      const float4 v1 = reinterpret_cast<const float4*>(src)[j * 2 + 1];
      bf16x8 o = { (bf16)v0.x, (bf16)v0.y, (bf16)v0.z, (bf16)v0.w,
                   (bf16)v1.x, (bf16)v1.y, (bf16)v1.z, (bf16)v1.w };
      reinterpret_cast<bf16x8*>(dst)[j] = o;
    }
  } else {
    const int KD = 4096, E = 2048;
    const int b2 = blockIdx.x - CAST_B;            // 0..2047
    const int k0 = (b2 & 63) * 64, e0 = (b2 >> 6) * 64;
    const int er = (tid & 15) * 4;
    const int kr = tid >> 4;
#pragma unroll
    for (int p = 0; p < 4; ++p) {
      const int k = kr + p * 16;
      const float pr = prior[k0 + k];
      const float4 v = *reinterpret_cast<const float4*>(dic + (size_t)(k0 + k) * E + e0 + er);
      bf16x4 db = { (bf16)v.x, (bf16)v.y, (bf16)v.z, (bf16)v.w };
      *reinterpret_cast<bf16x4*>(dicb + (size_t)(k0 + k) * E + e0 + er) = db;
      t[er + 0][k] = (bf16)(v.x * pr);
      t[er + 1][k] = (bf16)(v.y * pr);
      t[er + 2][k] = (bf16)(v.z * pr);
      t[er + 3][k] = (bf16)(v.w * pr);
    }
    __syncthreads();
    const int e = tid >> 2, kc = (tid & 3) * 16;
    ushort8 a = *reinterpret_cast<ushort8*>(&t[e][kc]);
    ushort8 b = *reinterpret_cast<ushort8*>(&t[e][kc + 8]);
    unsigned short* dst = (unsigned short*)w3t + (size_t)(e0 + e) * KD + k0 + kc;
    *reinterpret_cast<ushort8*>(dst) = a;
    *reinterpret_cast<ushort8*>(dst + 8) = b;
  }
}

// ---- fallback rowsum of expS: one wave per row (4096 bf16), memory-bound ----
__global__ __launch_bounds__(256) void rowsum_bf16(const unsigned short* __restrict__ S,
                                                   float* __restrict__ sums) {
  const int row = blockIdx.x * 4 + (threadIdx.x >> 6);
  const int lane = threadIdx.x & 63;
  const unsigned short* r = S + (size_t)row * 4096;
  float s = 0.f;
#pragma unroll
  for (int i = 0; i < 8; ++i) {
    ushort8 v = *reinterpret_cast<const ushort8*>(r + i * 512 + lane * 8);
#pragma unroll
    for (int j = 0; j < 8; ++j) s += __uint_as_float(((unsigned)v[j]) << 16);
  }
#pragma unroll
  for (int o = 32; o; o >>= 1) s += __shfl_xor(s, o);
  if (lane == 0) sums[row] = s;
}

// ============ 8-phase NT GEMM body, MINIMAL-BARRIER wave-slip ============
// R23 body with ONE change: setprio removed from the BN==256 path (T5 is
// structure-conditional; in the slip regime it plausibly starves the ds_read-
// issuing waves whose progress IS the cross-wave LDS||MFMA overlap).
// Barrier/staging/vmcnt ledgers identical to R19/R21 (verified).
template <int EPI, int BN>
__device__ __forceinline__ void gemm_body(
    const bf16* __restrict__ A, const bf16* __restrict__ B,
    const float* __restrict__ aux, float* __restrict__ psum,
    void* __restrict__ Cout, int M, int N, int K, float scale, int nparts,
    int orig, int nwg, char* lds) {
  constexpr int BUFSZ = 32768 + BN * 128;        // A 32KB + B
  constexpr int BOFF = 32768;
  constexpr int TM = (BN == 256) ? 128 : 64;
  constexpr int MI = TM / 16;
  constexpr int NI = 4;
  const int tid = threadIdx.x;
  const int lane = tid & 63, w = tid >> 6;

  // bijective XCD chunking (m204) over THIS problem's sub-grid, n-fast within chunk
  const int gridN = N / BN;
  int wgid;
  { const int q = nwg >> 3, r = nwg & 7, x = orig & 7, rest = orig >> 3;
    wgid = (x < r ? x * (q + 1) : r * (q + 1) + (x - r) * q) + rest; }
  const int m0 = (wgid / gridN) * 256;
  const int n0 = (wgid % gridN) * BN;

  // staging source: pre-swizzled chunk so linear LDS dest = swizzled layout
  const int srow = lane >> 3;                         // 0..7
  const int scol = ((lane & 7) ^ srow) * 8;           // chunk^row&7, elems
  const bf16* gA = A + (size_t)(m0 + w * 8 + srow) * K + scol;
  const bf16* gB = B + (size_t)(n0 + w * 8 + srow) * K + scol;

  auto stA = [&](char* dst, int u, int h) {
    gload16(gA + (size_t)(h * 128) * K + (size_t)u * 64, dst + h * 16384 + w * 1024);
    gload16(gA + (size_t)(h * 128 + 64) * K + (size_t)u * 64, dst + h * 16384 + 8192 + w * 1024);
  };
  auto stB = [&](char* dst, int u, int h) {
    gload16(gB + (size_t)(h * 128) * K + (size_t)u * 64, dst + BOFF + h * 16384 + w * 1024);
    gload16(gB + (size_t)(h * 128 + 64) * K + (size_t)u * 64, dst + BOFF + h * 16384 + 8192 + w * 1024);
  };

  // fragment read bases (swizzled)
  const int fr = lane & 15, hi = lane >> 4;
  int wm, wn;
  if constexpr (BN == 256) { wm = w >> 2; wn = w & 3; }
  else                     { wm = w >> 1; wn = w & 1; }
  const int abase = (wm * TM + fr) * 128 + ((hi ^ (fr & 7)) << 4);
  const int bbase = BOFF + (wn * 64 + fr) * 128 + ((hi ^ (fr & 7)) << 4);
#define RD_A(b, mi, ks) (*(const bf16x8*)((b) + ((abase + (mi) * 2048) ^ ((ks) << 6))))
#define RD_B(b, ni, ks) (*(const bf16x8*)((b) + ((bbase + (ni) * 2048) ^ ((ks) << 6))))

  f32x4 acc[MI][NI] = {};
  const int NT = K >> 6;

  // prologue: A(0), B(0), B(1); prove A(0)+B(0)
  stA(lds, 0, 0); stA(lds, 0, 1);
  stB(lds, 0, 0);
  if constexpr (BN == 256) stB(lds, 0, 1);
  stB(lds + BUFSZ, 1, 0);
  if constexpr (BN == 256) { stB(lds + BUFSZ, 1, 1); VMCNT(4); }
  else                     { VMCNT(2); }
  BAR();

  for (int u = 0; u < NT; ++u) {
    char* b  = lds + (size_t)(u & 1) * BUFSZ;
    char* bn = lds + (size_t)((u + 1) & 1) * BUFSZ;
    bf16x8 bb[2][NI], a[2][2];
    const bool sA = (u + 1) < NT, sB = (u + 2) < NT;

    if constexpr (BN == 256) {
      // ---- q1: B all + A(0,1); stage A-lo(u+1); lgkm0; MFMA  (no barrier) ----
      a[0][0] = RD_A(b, 0, 0); a[0][1] = RD_A(b, 0, 1);
      a[1][0] = RD_A(b, 1, 0); a[1][1] = RD_A(b, 1, 1);
#pragma unroll
      for (int ni = 0; ni < NI; ++ni) { bb[0][ni] = RD_B(b, ni, 0); bb[1][ni] = RD_B(b, ni, 1); }
      if (sA) stA(bn, u + 1, 0);
      LGKM0();
#pragma unroll
      for (int m2 = 0; m2 < 2; ++m2)
#pragma unroll
        for (int ni = 0; ni < NI; ++ni) {
          acc[m2][ni] = __builtin_amdgcn_mfma_f32_16x16x32_bf16(a[m2][0], bb[0][ni], acc[m2][ni], 0, 0, 0);
          acc[m2][ni] = __builtin_amdgcn_mfma_f32_16x16x32_bf16(a[m2][1], bb[1][ni], acc[m2][ni], 0, 0, 0);
        }
      // ---- q2: A(2,3); stage A-hi(u+1); lgkm0; MFMA  (no barrier) ----
      a[0][0] = RD_A(b, 2, 0); a[0][1] = RD_A(b, 2, 1);
      a[1][0] = RD_A(b, 3, 0); a[1][1] = RD_A(b, 3, 1);
      if (sA) stA(bn, u + 1, 1);
      LGKM0();
#pragma unroll
      for (int m2 = 0; m2 < 2; ++m2)
#pragma unroll
        for (int ni = 0; ni < NI; ++ni) {
          acc[2 + m2][ni] = __builtin_amdgcn_mfma_f32_16x16x32_bf16(a[m2][0], bb[0][ni], acc[2 + m2][ni], 0, 0, 0);
          acc[2 + m2][ni] = __builtin_amdgcn_mfma_f32_16x16x32_bf16(a[m2][1], bb[1][ni], acc[2 + m2][ni], 0, 0, 0);
        }
      // ---- q3: BAR (collectivizes q1/q2 drains); A(4,5); stage B-lo(u+2) ----
      BAR();
      a[0][0] = RD_A(b, 4, 0); a[0][1] = RD_A(b, 4, 1);
      a[1][0] = RD_A(b, 5, 0); a[1][1] = RD_A(b, 5, 1);
      if (sB) stB(b, u + 2, 0);
      LGKM0();
#pragma unroll
      for (int m2 = 0; m2 < 2; ++m2)
#pragma unroll
        for (int ni = 0; ni < NI; ++ni) {
          acc[4 + m2][ni] = __builtin_amdgcn_mfma_f32_16x16x32_bf16(a[m2][0], bb[0][ni], acc[4 + m2][ni], 0, 0, 0);
          acc[4 + m2][ni] = __builtin_amdgcn_mfma_f32_16x16x32_bf16(a[m2][1], bb[1][ni], acc[4 + m2][ni], 0, 0, 0);
        }
      // ---- q4: A(6,7); stage B-hi(u+2); vmcnt(4); lgkm0; MFMA; END BAR ----
      a[0][0] = RD_A(b, 6, 0); a[0][1] = RD_A(b, 6, 1);
      a[1][0] = RD_A(b, 7, 0); a[1][1] = RD_A(b, 7, 1);
      if (sB) stB(b, u + 2, 1);
      if (sB) VMCNT(4); else VMCNT(0);
      LGKM0();
#pragma unroll
      for (int m2 = 0; m2 < 2; ++m2)
#pragma unroll
        for (int ni = 0; ni < NI; ++ni) {
          acc[6 + m2][ni] = __builtin_amdgcn_mfma_f32_16x16x32_bf16(a[m2][0], bb[0][ni], acc[6 + m2][ni], 0, 0, 0);
          acc[6 + m2][ni] = __builtin_amdgcn_mfma_f32_16x16x32_bf16(a[m2][1], bb[1][ni], acc[6 + m2][ni], 0, 0, 0);
        }
      BAR();   // re-lockstep: collectivizes vmcnt(4) + lgkm0(q4)
    } else {
      // ---- BN==128 slip (R21-verified, setprio retained) ----
      a[0][0] = RD_A(b, 0, 0); a[0][1] = RD_A(b, 0, 1);
      a[1][0] = RD_A(b, 1, 0); a[1][1] = RD_A(b, 1, 1);
#pragma unroll
      for (int ni = 0; ni < NI; ++ni) { bb[0][ni] = RD_B(b, ni, 0); bb[1][ni] = RD_B(b, ni, 1); }
      if (sA) { stA(bn, u + 1, 0); stA(bn, u + 1, 1); }
      LGKM0();
      __builtin_amdgcn_s_setprio(1);
#pragma unroll
      for (int m2 = 0; m2 < 2; ++m2)
#pragma unroll
        for (int ni = 0; ni < NI; ++ni) {
          acc[m2][ni] = __builtin_amdgcn_mfma_f32_16x16x32_bf16(a[m2][0], bb[0][ni], acc[m2][ni], 0, 0, 0);
          acc[m2][ni] = __builtin_amdgcn_mfma_f32_16x16x32_bf16(a[m2][1], bb[1][ni], acc[m2][ni], 0, 0, 0);
        }
      __builtin_amdgcn_s_setprio(0);
      BAR();
      a[0][0] = RD_A(b, 2, 0); a[0][1] = RD_A(b, 2, 1);
      a[1][0] = RD_A(b, 3, 0); a[1][1] = RD_A(b, 3, 1);
      if (sB) stB(b, u + 2, 0);
      if (sB) VMCNT(2); else VMCNT(0);
      LGKM0();
      __builtin_amdgcn_s_setprio(1);
#pragma unroll
      for (int m2 = 0; m2 < 2; ++m2)
#pragma unroll
        for (int ni = 0; ni < NI; ++ni) {
          acc[2 + m2][ni] = __builtin_amdgcn_mfma_f32_16x16x32_bf16(a[m2][0], bb[0][ni], acc[2 + m2][ni], 0, 0, 0);
          acc[2 + m2][ni] = __builtin_amdgcn_mfma_f32_16x16x32_bf16(a[m2][1], bb[1][ni], acc[2 + m2][ni], 0, 0, 0);
        }
      __builtin_amdgcn_s_setprio(0);
      BAR();
    }
  }
#undef RD_A
#undef RD_B

  // ---- EPI==2: gather this block's 256 row sums (nparts partials each) ----
  float* lsum = (float*)lds;
  if constexpr (EPI == 2) {
    if (tid < 256) {
      const float* p = aux + (size_t)(m0 + tid) * nparts;
      float s = 0.f;
      for (int bp = 0; bp < nparts; ++bp) s += p[bp];
      lsum[tid] = s;
    }
    __syncthreads();
  }

  // epilogue: C/D layout col = lane&15, row = (lane>>4)*4 + j  [m89-verified]
  const int lro = hi * 4;
  if constexpr (EPI == 2) {
#pragma unroll
    for (int mi = 0; mi < MI; ++mi)
#pragma unroll
      for (int j = 0; j < 4; ++j) {
        const int lr = wm * TM + mi * 16 + lro + j;
        const float inv = 1.0f / lsum[lr];   // same-addr across fr -> LDS broadcast
        const size_t grow = (size_t)(m0 + lr) * N;
#pragma unroll
        for (int ni = 0; ni < NI; ++ni)
          ((float*)Cout)[grow + n0 + wn * 64 + ni * 16 + fr] = acc[mi][ni][j] * inv;
      }
  } else {
    float rs[MI][4];
    if constexpr (EPI == 1) {
#pragma unroll
      for (int mi = 0; mi < MI; ++mi)
#pragma unroll
        for (int j = 0; j < 4; ++j) rs[mi][j] = 0.f;
    }
#pragma unroll
    for (int ni = 0; ni < NI; ++ni) {
      const int gcol = n0 + wn * 64 + ni * 16 + fr;
      float bvs = 0.f;
      if constexpr (EPI == 0) bvs = aux[gcol];
#pragma unroll
      for (int mi = 0; mi < MI; ++mi) {
        const int grow = m0 + wm * TM + mi * 16 + lro;
#pragma unroll
        for (int j = 0; j < 4; ++j) {
          float c = acc[mi][ni][j] * scale + bvs;
          if constexpr (EPI == 1) { c = __expf(c); rs[mi][j] += c; }
          ((bf16*)Cout)[(size_t)(grow + j) * N + gcol] = (bf16)c;
        }
      }
    }
    if constexpr (EPI == 1) {
      if (psum != nullptr) {
        float* wsum = (float*)lds;   // [4 wn][256 rows] = 4 KB (post-loop, LDS dead)
        __syncthreads();             // all waves exited K-loop before LDS reuse
#pragma unroll
        for (int mi = 0; mi < MI; ++mi)
#pragma unroll
          for (int j = 0; j < 4; ++j) {
            float s = rs[mi][j];
            s += __shfl_xor(s, 1); s += __shfl_xor(s, 2);
            s += __shfl_xor(s, 4); s += __shfl_xor(s, 8);
            if (fr == 0) wsum[wn * 256 + wm * TM + mi * 16 + lro + j] = s;
          }
        __syncthreads();
        if (tid < 256) {
          const float s = wsum[tid] + wsum[256 + tid] + wsum[512 + tid] + wsum[768 + tid];
          psum[(size_t)(m0 + tid) * 16 + (n0 >> 8)] = s;
        }
      }
    }
  }
}

template <int EPI, int BN>
__global__ __launch_bounds__(512, 2) void gemm8(
    const bf16* __restrict__ A, const bf16* __restrict__ B,
    const float* __restrict__ aux, float* __restrict__ psum,
    void* __restrict__ Cout, int M, int N, int K, float scale, int nparts) {
  extern __shared__ char lds[];
  gemm_body<EPI, BN>(A, B, aux, psum, Cout, M, N, K, scale, nparts,
                     blockIdx.x, gridDim.x, lds);
}

// ---- fused independent G2+G3 in one dispatch (fills the CUs G3 alone leaves idle) ----
__global__ __launch_bounds__(512, 2) void gemm_g23(
    const bf16* __restrict__ A2, const bf16* __restrict__ B2,
    const float* __restrict__ b2, bf16* __restrict__ C2,
    const bf16* __restrict__ A3, const bf16* __restrict__ B3,
    const float* __restrict__ b3, bf16* __restrict__ C3,
    int M, int D, int E, int KD, int g2n) {
  extern __shared__ char lds[];
  if ((int)blockIdx.x < g2n)
    gemm_body<0, 256>(A2, B2, b2, nullptr, C2, M, D, D, 1.0f, 0,
                      blockIdx.x, g2n, lds);
  else
    gemm_body<0, 128>(A3, B3, b3, nullptr, C3, KD, D, E, 1.0f, 0,
                      blockIdx.x - g2n, gridDim.x - g2n, lds);
}

extern "C" void kernel_launch(void* const* d_in, const int* in_sizes, int n_in,
                              void* d_out, int out_size, void* d_ws, size_t ws_size,
                              hipStream_t stream) {
  const float* y     = (const float*)d_in[0];  // [16384,1024]
  const float* Wy_w  = (const float*)d_in[1];  // [1024,1024]
  const float* Wy_b  = (const float*)d_in[2];  // [1024]
  const float* Wz_w  = (const float*)d_in[3];  // [1024,2048]
  const float* Wz_b  = (const float*)d_in[4];  // [1024]
  const float* dic   = (const float*)d_in[5];  // [4096,2048]
  const float* prior = (const float*)d_in[6];  // [4096]
  float* z = (float*)d_out;                    // [16384,2048]

  const int M = 16384, D = 1024, E = 2048, KD = 4096;

  char* ws = (char*)d_ws;
  bf16* w3t  = (bf16*)(ws);                        // [0, 16M)
  bf16* h    = (bf16*)(ws + ((size_t)16 << 20));   // [16M, 48M)
  bf16* dzb  = (bf16*)(ws + ((size_t)48 << 20));   // [48M, 56M)
  bf16* S    = (bf16*)(ws + ((size_t)56 << 20));   // [56M, 184M)  expS after G4
  bf16* yb   = (bf16*)(ws + ((size_t)56 << 20));   // cast overlays inside S (dead pre-G4)
  bf16* Wyb  = (bf16*)(ws + ((size_t)88 << 20));
  bf16* Wzb  = (bf16*)(ws + ((size_t)90 << 20));
  bf16* dicb = (bf16*)(ws + ((size_t)94 << 20));

  // psum TAIL slab [184M, 185M): outside every live region during G4.
  const bool fused_sum = ws_size >= ((size_t)185 << 20);
  float* psum = fused_sum ? (float*)(ws + ((size_t)184 << 20)) : nullptr;
  float* sums = (float*)(ws + ((size_t)16 << 20));  // fallback: h region, dead after G4

  // 0+1) all casts + dic pass in ONE 4096-block dispatch
  prep_all<<<CAST_B + 2048, 256, 0, stream>>>(
      y, yb, M * D / 8, Wy_w, Wyb, D * D / 8, Wz_w, Wzb, D * E / 8,
      dic, prior, dicb, w3t);
  // 2+3) h = yb.Wyb^T + Wy_b  ||  dz = dicb.Wzb^T + Wz_b  (one 384-block dispatch)
  {
    const int g2n = (M / 256) * (D / 256);            // 256
    const int g3n = (KD / 256) * (D / 128);           // 128
    gemm_g23<<<g2n + g3n, 512, 131072, stream>>>(
        yb, Wyb, Wy_b, h, dicb, Wzb, Wz_b, dzb, M, D, E, KD, g2n);
  }
  // 4) expS = exp(h . dz^T / 32) -> bf16 [16384,4096] grid 1024
  gemm8<1, 256><<<(M / 256) * (KD / 256), 512, 131072, stream>>>(
      h, dzb, nullptr, psum, S, M, KD, D, 0.03125f, 0);
  if (!fused_sum) {
    rowsum_bf16<<<M / 4, 256, 0, stream>>>((const unsigned short*)S, sums);
  }
  // 5+6) z = (expS . w3t^T) / rowsum -> f32 [16384,2048]  grid 512
  gemm8<2, 256><<<(M / 256) * (E / 256), 512, 131072, stream>>>(
      S, w3t, fused_sum ? psum : sums, nullptr, z, M, E, KD, 1.0f,
      fused_sum ? 16 : 1);
}